// Round 1
// baseline (934.665 us; speedup 1.0000x reference)
//
#include <hip/hip_runtime.h>
#include <hip/hip_bf16.h>

// ---------------- constants ----------------
namespace {
constexpr int Bn  = 64;    // batch
constexpr int Cn  = 64;    // sensor channels / graph nodes
constexpr int DIN = 512;
constexpr int C1O = 32, C2O = 64;
constexpr int L1O = 249, L1P = 124;   // conv1 out len, pooled
constexpr int L2O = 55,  L2P = 27;    // conv2 out len, pooled
constexpr int FIN1 = 512;             // lin1 out features = cheby1 Fin
constexpr int LIN1K = C2O * L2P;      // 1728

// ws offsets (in floats)
constexpr long S1M = 0;          // 2048 conv1 bn mean
constexpr long S1I = 2048;       // 2048 conv1 bn invstd
constexpr long S2S = 4096;       // 4096 conv2 sum (zeroed)
constexpr long S2Q = 8192;       // 4096 conv2 sumsq (zeroed)
constexpr long S2M = 12288;      // 4096
constexpr long S2I = 16384;      // 4096
constexpr long LR0 = 20480;      // 4096
constexpr long LR1 = 24576;      // 1024
constexpr long W1R = 25600;      // 5*64*512 = 163840  (cl1_w repack [k][o][f])
constexpr long W2R = 189440;     // 5*128*64 = 40960   (cl2_w repack [k][o][f])
constexpr long R1  = 230400;     // p1: 64*64*32*124 = 16252928 ; later q: 64*64*64*27 = 7077888
constexpr long R2  = 16483328;   // y2: 64*64*64*55 = 14417920 ; later xk: 5*2097152 = 10485760
constexpr long COUT= 30901248;   // 64*64*512 = 2097152
constexpr long CH1 = 32998400;   // 64*64*64 = 262144
constexpr long X2K = 33260544;   // 5*32*64*64 = 655360
constexpr long CH2 = 33915904;   // 64*32*128 = 262144
constexpr long FCI = 34178048;   // 64*2048 = 131072
constexpr long FO1 = 34309120;   // 64*512 = 32768
}

// ---------------- prep: Lr matrices + cheby weight repack ----------------
__global__ void prep_kernel(const float* __restrict__ L0, const float* __restrict__ L1m,
                            const int* __restrict__ lmax0, const int* __restrict__ lmax1,
                            const float* __restrict__ cl1w, const float* __restrict__ cl2w,
                            float* __restrict__ ws)
{
    int idx = blockIdx.x * 256 + threadIdx.x;
    float inv0 = 2.0f / (float)lmax0[0];
    float inv1 = 2.0f / (float)lmax1[0];
    if (idx < 4096) {
        int i = idx / 64, j = idx % 64;
        ws[LR0 + idx] = L0[idx] * inv0 - (i == j ? 1.0f : 0.0f);
    } else if (idx < 5120) {
        int t = idx - 4096; int i = t / 32, j = t % 32;
        ws[LR1 + t] = L1m[t] * inv1 - (i == j ? 1.0f : 0.0f);
    } else if (idx < 5120 + 163840) {
        int t = idx - 5120;
        int k = t / 32768; int r = t % 32768; int o = r / 512, f = r % 512;
        ws[W1R + t] = cl1w[o * 2560 + f * 5 + k];
    } else if (idx < 5120 + 163840 + 40960) {
        int t = idx - 5120 - 163840;
        int k = t / 8192; int r = t % 8192; int o = r / 64, f = r % 64;
        ws[W2R + t] = cl2w[o * 320 + f * 5 + k];
    }
}

// ---------------- conv1 stats: one block per (c,o) ----------------
__global__ __launch_bounds__(256) void conv1_stats_kernel(const float* __restrict__ inp,
    const float* __restrict__ w1, const float* __restrict__ b1, float* __restrict__ ws)
{
    int co = blockIdx.x; int c = co >> 5;
    float w[16];
#pragma unroll
    for (int t = 0; t < 16; ++t) w[t] = w1[co * 16 + t];
    float bias = b1[co];
    float s = 0.f, q = 0.f;
    for (int idx = threadIdx.x; idx < Bn * L1O; idx += 256) {
        int b = idx / L1O, l = idx % L1O;
        const float* ip = inp + (b * Cn + c) * DIN + 2 * l;
        float acc = bias;
#pragma unroll
        for (int t = 0; t < 16; ++t) acc = fmaf(ip[t], w[t], acc);
        float y = fmaxf(acc, 0.f);
        s += y; q += y * y;
    }
    __shared__ float rs[256], rq[256];
    rs[threadIdx.x] = s; rq[threadIdx.x] = q;
    __syncthreads();
    for (int st = 128; st > 0; st >>= 1) {
        if (threadIdx.x < st) { rs[threadIdx.x] += rs[threadIdx.x + st]; rq[threadIdx.x] += rq[threadIdx.x + st]; }
        __syncthreads();
    }
    if (threadIdx.x == 0) {
        float N = (float)(Bn * L1O);
        float m = rs[0] / N, v = rq[0] / N - m * m;
        ws[S1M + co] = m; ws[S1I + co] = rsqrtf(v + 1e-5f);
    }
}

// ---------------- conv1 recompute + bn + maxpool -> p1 [c][b][o][124] ----------------
__global__ __launch_bounds__(256) void conv1_bnpool_kernel(const float* __restrict__ inp,
    const float* __restrict__ w1, const float* __restrict__ b1,
    const float* __restrict__ g, const float* __restrict__ be,
    const float* __restrict__ ws, float* __restrict__ p1)
{
    int co = blockIdx.x; int c = co >> 5, o = co & 31;
    float w[16];
#pragma unroll
    for (int t = 0; t < 16; ++t) w[t] = w1[co * 16 + t];
    float bias = b1[co];
    float m = ws[S1M + co], inv = ws[S1I + co];
    float sc = inv * g[co], sh = be[co] - m * sc;
    for (int idx = threadIdx.x; idx < Bn * L1P; idx += 256) {
        int b = idx / L1P, j = idx % L1P;
        const float* ip = inp + (b * Cn + c) * DIN + 4 * j;
        float a0 = bias, a1 = bias;
#pragma unroll
        for (int t = 0; t < 16; ++t) { a0 = fmaf(ip[t], w[t], a0); a1 = fmaf(ip[t + 2], w[t], a1); }
        float r0 = fmaxf(a0, 0.f) * sc + sh;
        float r1 = fmaxf(a1, 0.f) * sc + sh;
        p1[((long)(c * Bn + b) * C1O + o) * L1P + j] = fmaxf(r0, r1);
    }
}

// ---------------- conv2 as batched im2col GEMM + relu + stats atomics ----------------
// out y2[c][b][o2][l]; A[m=(b,l)][k=(ci,t)] = p1[c][b][ci][2l+t]; W[o2][k] = conv2_w[c]
__global__ __launch_bounds__(256) void conv2_gemm_kernel(const float* __restrict__ p1,
    const float* __restrict__ w2, const float* __restrict__ b2, float* __restrict__ y2,
    float* __restrict__ s2s, float* __restrict__ s2q)
{
    int c = blockIdx.z;
    int m0 = blockIdx.y * 64;
    __shared__ float As[32][68];
    __shared__ float Bs[32][68];
    int tid = threadIdx.x, tx = tid & 15, ty = tid >> 4;
    int lr = tid >> 3, lq = tid & 7;
    float acc[4][4] = {};
    const float* wbase = w2 + (long)c * C2O * 512;
    int mA = m0 + lr, mB = m0 + lr + 32;
    int bA = mA / L2O, lA = mA % L2O;
    int bB = mB / L2O, lB = mB % L2O;
    for (int k0 = 0; k0 < 512; k0 += 32) {
        int kbase = k0 + 4 * lq;
        int ci = kbase >> 4, t0 = kbase & 15;
        const float* pA = p1 + ((long)(c * Bn + bA) * C1O + ci) * L1P + 2 * lA + t0;
        const float* pB = p1 + ((long)(c * Bn + bB) * C1O + ci) * L1P + 2 * lB + t0;
        float a0[4], a1[4];
#pragma unroll
        for (int i = 0; i < 4; ++i) { a0[i] = pA[i]; a1[i] = pB[i]; }
        float4 w0 = *(const float4*)&wbase[(long)lr * 512 + kbase];
        float4 w1v = *(const float4*)&wbase[(long)(lr + 32) * 512 + kbase];
        __syncthreads();
#pragma unroll
        for (int i = 0; i < 4; ++i) { As[4 * lq + i][lr] = a0[i]; As[4 * lq + i][lr + 32] = a1[i]; }
        Bs[4 * lq + 0][lr] = w0.x; Bs[4 * lq + 1][lr] = w0.y; Bs[4 * lq + 2][lr] = w0.z; Bs[4 * lq + 3][lr] = w0.w;
        Bs[4 * lq + 0][lr + 32] = w1v.x; Bs[4 * lq + 1][lr + 32] = w1v.y; Bs[4 * lq + 2][lr + 32] = w1v.z; Bs[4 * lq + 3][lr + 32] = w1v.w;
        __syncthreads();
#pragma unroll
        for (int kk = 0; kk < 32; ++kk) {
            float a[4], bb[4];
#pragma unroll
            for (int i = 0; i < 4; ++i) a[i] = As[kk][4 * ty + i];
#pragma unroll
            for (int j = 0; j < 4; ++j) bb[j] = Bs[kk][4 * tx + j];
#pragma unroll
            for (int i = 0; i < 4; ++i)
#pragma unroll
                for (int j = 0; j < 4; ++j) acc[i][j] = fmaf(a[i], bb[j], acc[i][j]);
        }
    }
    float cs[4] = {}, cq[4] = {};
#pragma unroll
    for (int i = 0; i < 4; ++i) {
        int m = m0 + 4 * ty + i; int b = m / L2O, l = m % L2O;
#pragma unroll
        for (int j = 0; j < 4; ++j) {
            int o2 = 4 * tx + j;
            float v = acc[i][j] + b2[c * C2O + o2];
            float y = fmaxf(v, 0.f);
            y2[((long)(c * Bn + b) * C2O + o2) * L2O + l] = y;
            cs[j] += y; cq[j] += y * y;
        }
    }
    __syncthreads();
    float* r1 = &As[0][0]; float* r2 = &Bs[0][0];
#pragma unroll
    for (int j = 0; j < 4; ++j) { r1[(4 * tx + j) * 16 + ty] = cs[j]; r2[(4 * tx + j) * 16 + ty] = cq[j]; }
    __syncthreads();
    if (tid < 64) {
        float ss = 0.f, qq = 0.f;
        for (int t = 0; t < 16; ++t) { ss += r1[tid * 16 + t]; qq += r2[tid * 16 + t]; }
        atomicAdd(&s2s[c * C2O + tid], ss);
        atomicAdd(&s2q[c * C2O + tid], qq);
    }
}

__global__ void stats2_fin_kernel(float* ws)
{
    int i = blockIdx.x * 256 + threadIdx.x;
    if (i < 4096) {
        float N = (float)(Bn * L2O);
        float m = ws[S2S + i] / N;
        float v = ws[S2Q + i] / N - m * m;
        ws[S2M + i] = m; ws[S2I + i] = rsqrtf(v + 1e-5f);
    }
}

// ---------------- conv2 bn + pool -> q [c][b][o2][27] ----------------
__global__ void bn2_pool_kernel(const float* __restrict__ y2, const float* __restrict__ ws,
    const float* __restrict__ g, const float* __restrict__ be, float* __restrict__ q)
{
    long idx = (long)blockIdx.x * 256 + threadIdx.x;
    if (idx >= (long)Cn * Bn * C2O * L2P) return;
    int j = idx % L2P; long r = idx / L2P;
    int o2 = r % C2O; long r2 = r / C2O; int b = r2 % Bn; int c = r2 / Bn;
    int co = c * C2O + o2;
    float sc = ws[S2I + co] * g[co], sh = be[co] - ws[S2M + co] * sc;
    const float* yb = y2 + ((long)(c * Bn + b) * C2O + o2) * L2O + 2 * j;
    q[idx] = fmaxf(sc * yb[0] + sh, sc * yb[1] + sh);
}

// ---------------- generic batched tiled GEMM: C = A[M,K] @ W[N,K]^T + bias (opt relu) ----------------
__global__ __launch_bounds__(256) void gemm_tn_kernel(const float* __restrict__ A, const float* __restrict__ W,
    const float* __restrict__ bias, float* __restrict__ Cm,
    int M, int N, int K, long sA, long sW, long sC, long sB, int relu)
{
    int bz = blockIdx.z;
    A += (long)bz * sA; W += (long)bz * sW; Cm += (long)bz * sC; bias += (long)bz * sB;
    int m0 = blockIdx.y * 64, n0 = blockIdx.x * 64;
    __shared__ float As[32][68];
    __shared__ float Bs[32][68];
    int tid = threadIdx.x, tx = tid & 15, ty = tid >> 4;
    int lr = tid >> 3, lq = tid & 7;
    float acc[4][4] = {};
    for (int k0 = 0; k0 < K; k0 += 32) {
        float4 a0 = *(const float4*)&A[(long)(m0 + lr) * K + k0 + 4 * lq];
        float4 a1 = *(const float4*)&A[(long)(m0 + lr + 32) * K + k0 + 4 * lq];
        float4 w0 = *(const float4*)&W[(long)(n0 + lr) * K + k0 + 4 * lq];
        float4 w1v = *(const float4*)&W[(long)(n0 + lr + 32) * K + k0 + 4 * lq];
        __syncthreads();
        As[4 * lq + 0][lr] = a0.x; As[4 * lq + 1][lr] = a0.y; As[4 * lq + 2][lr] = a0.z; As[4 * lq + 3][lr] = a0.w;
        As[4 * lq + 0][lr + 32] = a1.x; As[4 * lq + 1][lr + 32] = a1.y; As[4 * lq + 2][lr + 32] = a1.z; As[4 * lq + 3][lr + 32] = a1.w;
        Bs[4 * lq + 0][lr] = w0.x; Bs[4 * lq + 1][lr] = w0.y; Bs[4 * lq + 2][lr] = w0.z; Bs[4 * lq + 3][lr] = w0.w;
        Bs[4 * lq + 0][lr + 32] = w1v.x; Bs[4 * lq + 1][lr + 32] = w1v.y; Bs[4 * lq + 2][lr + 32] = w1v.z; Bs[4 * lq + 3][lr + 32] = w1v.w;
        __syncthreads();
#pragma unroll
        for (int kk = 0; kk < 32; ++kk) {
            float a[4], bb[4];
#pragma unroll
            for (int i = 0; i < 4; ++i) a[i] = As[kk][4 * ty + i];
#pragma unroll
            for (int j = 0; j < 4; ++j) bb[j] = Bs[kk][4 * tx + j];
#pragma unroll
            for (int i = 0; i < 4; ++i)
#pragma unroll
                for (int j = 0; j < 4; ++j) acc[i][j] = fmaf(a[i], bb[j], acc[i][j]);
        }
    }
#pragma unroll
    for (int i = 0; i < 4; ++i) {
#pragma unroll
        for (int j = 0; j < 4; ++j) {
            float v = acc[i][j] + bias[n0 + 4 * tx + j];
            if (relu) v = fmaxf(v, 0.f);
            Cm[(long)(m0 + 4 * ty + i) * N + n0 + 4 * tx + j] = v;
        }
    }
}

// ---------------- gather x0[v][b][f] = cout[perm[v]][b][f] ----------------
__global__ void gather_x0_kernel(const float* __restrict__ cout_, const int* __restrict__ perm,
                                 float* __restrict__ x0)
{
    long idx = (long)blockIdx.x * 256 + threadIdx.x;
    if (idx < (long)Cn * Bn * FIN1) {
        int v = idx / (Bn * FIN1); long r = idx % (Bn * FIN1);
        x0[idx] = cout_[(long)perm[v] * Bn * FIN1 + r];
    }
}

// ---------------- chebyshev recursion: Y = Lr@X (sub=0) or Y = 2*Lr@X - Xp ----------------
template<int V>
__global__ __launch_bounds__(256) void cheby_rec_kernel(const float* __restrict__ Lr,
    const float* __restrict__ X, const float* __restrict__ Xp, float* __restrict__ Y, int M, int sub)
{
    __shared__ float L[V * V];
    for (int i = threadIdx.x; i < V * V; i += 256) L[i] = Lr[i];
    __syncthreads();
    long m = (long)blockIdx.x * 256 + threadIdx.x;
    int v0 = blockIdx.y * 16;
    float acc[16] = {};
    for (int u = 0; u < V; ++u) {
        float x = X[(long)u * M + m];
#pragma unroll
        for (int i = 0; i < 16; ++i) acc[i] = fmaf(L[(v0 + i) * V + u], x, acc[i]);
    }
#pragma unroll
    for (int i = 0; i < 16; ++i) {
        long o = (long)(v0 + i) * M + m;
        Y[o] = sub ? (2.f * acc[i] - Xp[o]) : acc[i];
    }
}

// ---------------- cheby output GEMM: out[b][v][o] = relu( sum_k sum_f xk[k][v][b][f]*Wr[k][o][f] + bias[o] )
template<int V, int O, int FIN, int TM>
__global__ __launch_bounds__(256) void cheby_gemm_kernel(const float* __restrict__ xk,
    const float* __restrict__ Wr, const float* __restrict__ bias, float* __restrict__ out)
{
    int b = blockIdx.z, n0 = blockIdx.x * 64;
    __shared__ float Xs[32][V + 4];
    __shared__ float Ws[32][68];
    int tid = threadIdx.x, tx = tid & 15, ty = tid >> 4;
    float acc[TM][4] = {};
    for (int k = 0; k < 5; ++k) {
        const float* xb = xk + ((long)k * V * Bn + b) * FIN;
        const float* wb = Wr + (long)k * O * FIN;
        for (int f0 = 0; f0 < FIN; f0 += 32) {
            __syncthreads();
            for (int e = tid; e < V * 8; e += 256) {
                int v = e >> 3, qd = e & 7;
                float4 x4 = *(const float4*)&xb[(long)v * (Bn * FIN) + f0 + 4 * qd];
                Xs[4 * qd + 0][v] = x4.x; Xs[4 * qd + 1][v] = x4.y; Xs[4 * qd + 2][v] = x4.z; Xs[4 * qd + 3][v] = x4.w;
            }
            for (int e = tid; e < 64 * 8; e += 256) {
                int rr = e >> 3, qd = e & 7;
                float4 w4 = *(const float4*)&wb[(long)(n0 + rr) * FIN + f0 + 4 * qd];
                Ws[4 * qd + 0][rr] = w4.x; Ws[4 * qd + 1][rr] = w4.y; Ws[4 * qd + 2][rr] = w4.z; Ws[4 * qd + 3][rr] = w4.w;
            }
            __syncthreads();
#pragma unroll
            for (int kk = 0; kk < 32; ++kk) {
                float a[TM], bb[4];
#pragma unroll
                for (int i = 0; i < TM; ++i) a[i] = Xs[kk][TM * ty + i];
#pragma unroll
                for (int j = 0; j < 4; ++j) bb[j] = Ws[kk][4 * tx + j];
#pragma unroll
                for (int i = 0; i < TM; ++i)
#pragma unroll
                    for (int j = 0; j < 4; ++j) acc[i][j] = fmaf(a[i], bb[j], acc[i][j]);
            }
        }
    }
#pragma unroll
    for (int i = 0; i < TM; ++i) {
#pragma unroll
        for (int j = 0; j < 4; ++j) {
            int v = TM * ty + i, o = n0 + 4 * tx + j;
            float val = acc[i][j] + bias[o];
            out[((long)b * V + v) * O + o] = fmaxf(val, 0.f);   // relu before gbn
        }
    }
}

// ---------------- graph BN (per node over (B,F)) + graph max-pool over node pairs ----------------
// in y [B][V][F] (already relu'd). XOUT=1: out[j][b][f] (cheby layout); XOUT=0: out[b][j][f]
template<int Fdim, int XOUT>
__global__ __launch_bounds__(256) void gbn_gpool_kernel(const float* __restrict__ y,
    const float* __restrict__ g, const float* __restrict__ be, float eps, int V, float* __restrict__ out)
{
    int j = blockIdx.x; int v0 = 2 * j;
    int tid = threadIdx.x;
    float s0 = 0.f, q0 = 0.f, s1 = 0.f, q1 = 0.f;
    int Ntot = Bn * Fdim;
    for (int idx = tid; idx < Ntot; idx += 256) {
        int b = idx / Fdim, f = idx % Fdim;
        float a = y[((long)b * V + v0) * Fdim + f];
        float c = y[((long)b * V + v0 + 1) * Fdim + f];
        s0 += a; q0 += a * a; s1 += c; q1 += c * c;
    }
    __shared__ float red[4][256];
    red[0][tid] = s0; red[1][tid] = q0; red[2][tid] = s1; red[3][tid] = q1;
    __syncthreads();
    for (int st = 128; st > 0; st >>= 1) {
        if (tid < st) {
#pragma unroll
            for (int r = 0; r < 4; ++r) red[r][tid] += red[r][tid + st];
        }
        __syncthreads();
    }
    float N = (float)Ntot;
    float m0 = red[0][0] / N, i0 = rsqrtf(red[1][0] / N - m0 * m0 + eps);
    float m1 = red[2][0] / N, i1 = rsqrtf(red[3][0] / N - m1 * m1 + eps);
    float sc0 = i0 * g[v0], sh0 = be[v0] - m0 * sc0;
    float sc1 = i1 * g[v0 + 1], sh1 = be[v0 + 1] - m1 * sc1;
    for (int idx = tid; idx < Ntot; idx += 256) {
        int b = idx / Fdim, f = idx % Fdim;
        float a = y[((long)b * V + v0) * Fdim + f];
        float c = y[((long)b * V + v0 + 1) * Fdim + f];
        float r = fmaxf(sc0 * a + sh0, sc1 * c + sh1);
        long oidx = XOUT ? ((long)j * Bn + b) * Fdim + f : ((long)b * (V / 2) + j) * Fdim + f;
        out[oidx] = r;
    }
}

// ---------------- fc2 ----------------
__global__ void fc2_kernel(const float* __restrict__ x, const float* __restrict__ w,
                           const float* __restrict__ bv, float* __restrict__ out)
{
    int tid = threadIdx.x;   // 128 threads
    int b = tid >> 1, o = tid & 1;
    float acc = bv[o];
    for (int f = 0; f < 512; ++f) acc = fmaf(x[b * 512 + f], w[o * 512 + f], acc);
    out[tid] = acc;
}

// ---------------- launch ----------------
extern "C" void kernel_launch(void* const* d_in, const int* in_sizes, int n_in,
                              void* d_out, int out_size, void* d_ws, size_t ws_size,
                              hipStream_t stream)
{
    const float* inp    = (const float*)d_in[0];
    const float* L0     = (const float*)d_in[2];
    const float* L1m    = (const float*)d_in[3];
    const int*   lmax0  = (const int*)d_in[4];
    const int*   lmax1  = (const int*)d_in[5];
    const int*   perm   = (const int*)d_in[6];
    const float* conv1_w = (const float*)d_in[8];
    const float* conv1_b = (const float*)d_in[9];
    const float* bn1_g  = (const float*)d_in[10];
    const float* bn1_b  = (const float*)d_in[11];
    const float* conv2_w = (const float*)d_in[12];
    const float* conv2_b = (const float*)d_in[13];
    const float* bn2_g  = (const float*)d_in[14];
    const float* bn2_b  = (const float*)d_in[15];
    const float* lin1_w = (const float*)d_in[16];
    const float* lin1_b = (const float*)d_in[17];
    const float* cl1_w  = (const float*)d_in[18];
    const float* cl1_b  = (const float*)d_in[19];
    const float* gbn1_g = (const float*)d_in[20];
    const float* gbn1_b = (const float*)d_in[21];
    const float* cl2_w  = (const float*)d_in[22];
    const float* cl2_b  = (const float*)d_in[23];
    const float* gbn2_g = (const float*)d_in[24];
    const float* gbn2_b = (const float*)d_in[25];
    const float* fc1_w  = (const float*)d_in[26];
    const float* fc1_b  = (const float*)d_in[27];
    const float* fc2_w  = (const float*)d_in[28];
    const float* fc2_b  = (const float*)d_in[29];
    float* ws  = (float*)d_ws;
    float* out = (float*)d_out;

    // 0. prep: Lr0/Lr1 + cheby weight repacks
    prep_kernel<<<820, 256, 0, stream>>>(L0, L1m, lmax0, lmax1, cl1_w, cl2_w, ws);

    // 1. conv1 stats, then recompute+bn+pool -> p1 (at R1)
    conv1_stats_kernel<<<2048, 256, 0, stream>>>(inp, conv1_w, conv1_b, ws);
    conv1_bnpool_kernel<<<2048, 256, 0, stream>>>(inp, conv1_w, conv1_b, bn1_g, bn1_b, ws, ws + R1);

    // 2. conv2 GEMM (+relu+stats) -> y2 (at R2), stats finalize, bn+pool -> q (aliases R1)
    hipMemsetAsync(ws + S2S, 0, 8192 * sizeof(float), stream);
    conv2_gemm_kernel<<<dim3(1, 55, 64), 256, 0, stream>>>(ws + R1, conv2_w, conv2_b,
                                                           ws + R2, ws + S2S, ws + S2Q);
    stats2_fin_kernel<<<16, 256, 0, stream>>>(ws);
    bn2_pool_kernel<<<(Cn * Bn * C2O * L2P) / 256, 256, 0, stream>>>(ws + R2, ws, bn2_g, bn2_b, ws + R1);

    // 3. lin1: per-channel GEMM [64x1728]@[1728x512]^T + relu -> cout
    gemm_tn_kernel<<<dim3(8, 1, 64), 256, 0, stream>>>(ws + R1, lin1_w, lin1_b, ws + COUT,
        64, 512, LIN1K, (long)64 * LIN1K, (long)512 * LIN1K, (long)64 * 512, 512, 1);

    // 4. cheby layer 1 (xk aliases R2; y2 is dead)
    float* xk = ws + R2;
    const long XKS = (long)Cn * Bn * FIN1;   // 2097152
    gather_x0_kernel<<<8192, 256, 0, stream>>>(ws + COUT, perm, xk);
    cheby_rec_kernel<64><<<dim3(128, 4), 256, 0, stream>>>(ws + LR0, xk,           nullptr,      xk + XKS,     32768, 0);
    cheby_rec_kernel<64><<<dim3(128, 4), 256, 0, stream>>>(ws + LR0, xk + XKS,     xk,           xk + 2 * XKS, 32768, 1);
    cheby_rec_kernel<64><<<dim3(128, 4), 256, 0, stream>>>(ws + LR0, xk + 2 * XKS, xk + XKS,     xk + 3 * XKS, 32768, 1);
    cheby_rec_kernel<64><<<dim3(128, 4), 256, 0, stream>>>(ws + LR0, xk + 3 * XKS, xk + 2 * XKS, xk + 4 * XKS, 32768, 1);
    cheby_gemm_kernel<64, 64, 512, 4><<<dim3(1, 1, 64), 256, 0, stream>>>(xk, ws + W1R, cl1_b, ws + CH1);

    // 5. gbn1 + gpool1 -> x2k[0] in [v'][b][f] layout
    gbn_gpool_kernel<64, 1><<<32, 256, 0, stream>>>(ws + CH1, gbn1_g, gbn1_b, 64.0f, 64, ws + X2K);

    // 6. cheby layer 2
    float* x2k = ws + X2K;
    const long X2S = (long)32 * Bn * 64;     // 131072
    cheby_rec_kernel<32><<<dim3(16, 2), 256, 0, stream>>>(ws + LR1, x2k,           nullptr,      x2k + X2S,     4096, 0);
    cheby_rec_kernel<32><<<dim3(16, 2), 256, 0, stream>>>(ws + LR1, x2k + X2S,     x2k,          x2k + 2 * X2S, 4096, 1);
    cheby_rec_kernel<32><<<dim3(16, 2), 256, 0, stream>>>(ws + LR1, x2k + 2 * X2S, x2k + X2S,    x2k + 3 * X2S, 4096, 1);
    cheby_rec_kernel<32><<<dim3(16, 2), 256, 0, stream>>>(ws + LR1, x2k + 3 * X2S, x2k + 2 * X2S, x2k + 4 * X2S, 4096, 1);
    cheby_gemm_kernel<32, 128, 64, 2><<<dim3(2, 1, 64), 256, 0, stream>>>(x2k, ws + W2R, cl2_b, ws + CH2);

    // 7. gbn2 + gpool2 -> fc input [b][j*128+f]
    gbn_gpool_kernel<128, 0><<<16, 256, 0, stream>>>(ws + CH2, gbn2_g, gbn2_b, 128.0f, 32, ws + FCI);

    // 8. fc1 (+relu) and fc2
    gemm_tn_kernel<<<dim3(8, 1, 1), 256, 0, stream>>>(ws + FCI, fc1_w, fc1_b, ws + FO1,
        64, 512, 2048, 0, 0, 0, 0, 1);
    fc2_kernel<<<1, 128, 0, stream>>>(ws + FO1, fc2_w, fc2_b, out);
}

// Round 2
// 563.817 us; speedup vs baseline: 1.6577x; 1.6577x over previous
//
#include <hip/hip_runtime.h>
#include <hip/hip_bf16.h>

typedef __attribute__((ext_vector_type(8))) short short8;
typedef __attribute__((ext_vector_type(4))) float f32x4;

// ---------------- constants ----------------
namespace {
constexpr int Bn  = 64;    // batch
constexpr int Cn  = 64;    // sensor channels / graph nodes
constexpr int DIN = 512;
constexpr int C1O = 32, C2O = 64;
constexpr int L1O = 249, L1P = 124;   // conv1 out len, pooled
constexpr int L2O = 55,  L2P = 27;    // conv2 out len, pooled
constexpr int FIN1 = 512;             // lin1 out features = cheby1 Fin
constexpr int LIN1K = C2O * L2P;      // 1728

// stats region (float offsets)
constexpr long S1M = 0;          // 2048
constexpr long S1I = 2048;       // 2048
constexpr long S2S = 4096;       // 4096 (zeroed)
constexpr long S2Q = 8192;       // 4096 (zeroed)
constexpr long S2M = 12288;
constexpr long S2I = 16384;      // ends 20480 floats = 81920 B

// byte offsets into ws
constexpr long LR0_B = 90112;        // 4096 f
constexpr long LR1_B = 106496;       // 1024 f
constexpr long W1R_B = 110592;       // 163840 f -> 765952
constexpr long W2R_B = 765952;       // 40960 f  -> 929792
constexpr long W2B_B = 929792;       // 2097152 ushort -> 5124096
constexpr long P1B_B = 5124096;      // 16252928 ushort -> 37629952
constexpr long Y2_B  = 37629952;     // 14417920 f -> 95301632
constexpr long QB_B  = 95301632;     // 7077888 ushort -> 109457408
constexpr long CO_B  = 109457408;    // 2097152 f -> 117846016
constexpr long XK_B  = 5124096;      // alias p1b/y2 (both dead): 5*2097152 f -> 47067136
constexpr long CH1_B = 117846016;    // 262144 f
constexpr long X2K_B = 118894592;    // 655360 f
constexpr long CH2_B = 121516032;    // 262144 f
constexpr long FCI_B = 122564608;    // 131072 f
constexpr long FO1_B = 123088896;    // 32768 f
}

__device__ __forceinline__ unsigned short f2bf(float f) {
    union { float f; unsigned u; } v; v.f = f;
    unsigned r = v.u + 0x7FFFu + ((v.u >> 16) & 1u);
    return (unsigned short)(r >> 16);
}

__device__ __forceinline__ short8 cvt8(float4 a, float4 b) {
    float f[8] = {a.x, a.y, a.z, a.w, b.x, b.y, b.z, b.w};
    union { unsigned short s[8]; short8 v; } r;
#pragma unroll
    for (int i = 0; i < 8; ++i) r.s[i] = f2bf(f[i]);
    return r.v;
}

// ---------------- prep: Lr matrices + cheby weight repack + conv2_w -> bf16 ----------------
__global__ void prep_kernel(const float* __restrict__ L0, const float* __restrict__ L1m,
                            const int* __restrict__ lmax0, const int* __restrict__ lmax1,
                            const float* __restrict__ cl1w, const float* __restrict__ cl2w,
                            const float* __restrict__ conv2w, float* __restrict__ ws,
                            unsigned short* __restrict__ w2b)
{
    int idx = blockIdx.x * 256 + threadIdx.x;
    float inv0 = 2.0f / (float)lmax0[0];
    float inv1 = 2.0f / (float)lmax1[0];
    float* LR0p = (float*)((char*)ws + LR0_B);
    float* LR1p = (float*)((char*)ws + LR1_B);
    float* W1Rp = (float*)((char*)ws + W1R_B);
    float* W2Rp = (float*)((char*)ws + W2R_B);
    if (idx < 4096) {
        int i = idx / 64, j = idx % 64;
        LR0p[idx] = L0[idx] * inv0 - (i == j ? 1.0f : 0.0f);
    } else if (idx < 5120) {
        int t = idx - 4096; int i = t / 32, j = t % 32;
        LR1p[t] = L1m[t] * inv1 - (i == j ? 1.0f : 0.0f);
    } else if (idx < 5120 + 163840) {
        int t = idx - 5120;
        int k = t / 32768; int r = t % 32768; int o = r / 512, f = r % 512;
        W1Rp[t] = cl1w[o * 2560 + f * 5 + k];
    } else if (idx < 5120 + 163840 + 40960) {
        int t = idx - 5120 - 163840;
        int k = t / 8192; int r = t % 8192; int o = r / 64, f = r % 64;
        W2Rp[t] = cl2w[o * 320 + f * 5 + k];
    } else if (idx < 5120 + 163840 + 40960 + 2097152) {
        int t = idx - 5120 - 163840 - 40960;
        w2b[t] = f2bf(conv2w[t]);
    }
}

// ---------------- conv1 stats: one block per (c,o) ----------------
__global__ __launch_bounds__(256) void conv1_stats_kernel(const float* __restrict__ inp,
    const float* __restrict__ w1, const float* __restrict__ b1, float* __restrict__ ws)
{
    int co = blockIdx.x; int c = co >> 5;
    float w[16];
#pragma unroll
    for (int t = 0; t < 16; ++t) w[t] = w1[co * 16 + t];
    float bias = b1[co];
    float s = 0.f, q = 0.f;
    for (int idx = threadIdx.x; idx < Bn * L1O; idx += 256) {
        int b = idx / L1O, l = idx % L1O;
        const float* ip = inp + (b * Cn + c) * DIN + 2 * l;
        float acc = bias;
#pragma unroll
        for (int t = 0; t < 16; ++t) acc = fmaf(ip[t], w[t], acc);
        float y = fmaxf(acc, 0.f);
        s += y; q += y * y;
    }
    __shared__ float rs[256], rq[256];
    rs[threadIdx.x] = s; rq[threadIdx.x] = q;
    __syncthreads();
    for (int st = 128; st > 0; st >>= 1) {
        if (threadIdx.x < st) { rs[threadIdx.x] += rs[threadIdx.x + st]; rq[threadIdx.x] += rq[threadIdx.x + st]; }
        __syncthreads();
    }
    if (threadIdx.x == 0) {
        float N = (float)(Bn * L1O);
        float m = rs[0] / N, v = rq[0] / N - m * m;
        ws[S1M + co] = m; ws[S1I + co] = rsqrtf(v + 1e-5f);
    }
}

// ---------------- conv1 recompute + bn + maxpool -> p1b bf16 [c][b][o][124] ----------------
__global__ __launch_bounds__(256) void conv1_bnpool_kernel(const float* __restrict__ inp,
    const float* __restrict__ w1, const float* __restrict__ b1,
    const float* __restrict__ g, const float* __restrict__ be,
    const float* __restrict__ ws, unsigned short* __restrict__ p1)
{
    int co = blockIdx.x; int c = co >> 5, o = co & 31;
    float w[16];
#pragma unroll
    for (int t = 0; t < 16; ++t) w[t] = w1[co * 16 + t];
    float bias = b1[co];
    float m = ws[S1M + co], inv = ws[S1I + co];
    float sc = inv * g[co], sh = be[co] - m * sc;
    for (int idx = threadIdx.x; idx < Bn * L1P; idx += 256) {
        int b = idx / L1P, j = idx % L1P;
        const float* ip = inp + (b * Cn + c) * DIN + 4 * j;
        float a0 = bias, a1 = bias;
#pragma unroll
        for (int t = 0; t < 16; ++t) { a0 = fmaf(ip[t], w[t], a0); a1 = fmaf(ip[t + 2], w[t], a1); }
        float r0 = fmaxf(a0, 0.f) * sc + sh;
        float r1 = fmaxf(a1, 0.f) * sc + sh;
        p1[((long)(c * Bn + b) * C1O + o) * L1P + j] = f2bf(fmaxf(r0, r1));
    }
}

// ---------------- conv2 as batched im2col MFMA GEMM (bf16) + relu + stats ----------------
// y2[c][b][o2][55] fp32. A[m=(b,l)][k=(ci*16+t)] = p1b[c][b][ci][2l+t]; B[o2][k] = w2b[c]
__global__ __launch_bounds__(256) void conv2_mfma_kernel(const unsigned short* __restrict__ p1b,
    const unsigned short* __restrict__ w2b, const float* __restrict__ b2,
    float* __restrict__ y2, float* __restrict__ s2s, float* __restrict__ s2q)
{
    int c = blockIdx.y;
    int m0 = blockIdx.x * 64;
    __shared__ unsigned short Bl[64 * 512];   // 64KB, XOR-swizzled rows
    __shared__ float red[2][4][64];
    int tid = threadIdx.x;
    int w = tid >> 6, lane = tid & 63;
    int lx = lane & 15, g = lane >> 4;

    // stage B (w2b[c]: [64 o2][512 k]) into swizzled LDS, coalesced 16B chunks
    const unsigned short* wsrc = w2b + (long)c * 64 * 512;
#pragma unroll
    for (int it = 0; it < 16; ++it) {
        int j = it * 256 + tid;
        int n = j >> 6, kb = j & 63;
        uint4 val = *(const uint4*)(wsrc + n * 512 + kb * 8);
        int dst = (n * 1024 + kb * 16) ^ ((n & 7) << 4);
        *(uint4*)((char*)Bl + dst) = val;
    }
    __syncthreads();

    // A addressing: row m -> (b, lpos); k = kstep*32 + g*8 -> ci = 2*kstep + (g>>1), t0 = (g&1)*8
    int m = m0 + w * 16 + lx;
    int b = m / 55, lpos = m % 55;
    const unsigned short* abase = p1b + ((long)(c * 64 + b) * 32) * 124 + 2 * lpos + (g & 1) * 8;
    int cio = g >> 1;

    f32x4 acc[4] = {};
    for (int kstep = 0; kstep < 16; ++kstep) {
        const unsigned short* ap = abase + (kstep * 2 + cio) * 124;
        union { unsigned u[4]; short8 v; } af;
        af.u[0] = *(const unsigned*)(ap + 0);
        af.u[1] = *(const unsigned*)(ap + 2);
        af.u[2] = *(const unsigned*)(ap + 4);
        af.u[3] = *(const unsigned*)(ap + 6);
#pragma unroll
        for (int fi = 0; fi < 4; ++fi) {
            int n = fi * 16 + lx;
            int off = (n * 1024 + kstep * 64 + g * 16) ^ ((n & 7) << 4);
            short8 bfrag = *(const short8*)((char*)Bl + off);
            acc[fi] = __builtin_amdgcn_mfma_f32_16x16x32_bf16(af.v, bfrag, acc[fi], 0, 0, 0);
        }
    }

    // epilogue: C/D layout col = lane&15 (o2 within frag), row = g*4 + r
    float cs[4] = {}, cq[4] = {};
#pragma unroll
    for (int fi = 0; fi < 4; ++fi) {
        int o2 = fi * 16 + lx;
        float bia = b2[c * 64 + o2];
#pragma unroll
        for (int r = 0; r < 4; ++r) {
            int mm = m0 + w * 16 + g * 4 + r;
            int bb = mm / 55, ll = mm % 55;
            float y = fmaxf(acc[fi][r] + bia, 0.f);
            y2[((long)(c * 64 + bb) * 64 + o2) * 55 + ll] = y;
            cs[fi] += y; cq[fi] += y * y;
        }
    }
    // reduce rows within wave (over g groups)
#pragma unroll
    for (int fi = 0; fi < 4; ++fi) {
        cs[fi] += __shfl_xor(cs[fi], 16); cs[fi] += __shfl_xor(cs[fi], 32);
        cq[fi] += __shfl_xor(cq[fi], 16); cq[fi] += __shfl_xor(cq[fi], 32);
    }
    if (g == 0) {
#pragma unroll
        for (int fi = 0; fi < 4; ++fi) { red[0][w][fi * 16 + lx] = cs[fi]; red[1][w][fi * 16 + lx] = cq[fi]; }
    }
    __syncthreads();
    if (tid < 64) {
        float ss = red[0][0][tid] + red[0][1][tid] + red[0][2][tid] + red[0][3][tid];
        float qq = red[1][0][tid] + red[1][1][tid] + red[1][2][tid] + red[1][3][tid];
        atomicAdd(&s2s[c * 64 + tid], ss);
        atomicAdd(&s2q[c * 64 + tid], qq);
    }
}

__global__ void stats2_fin_kernel(float* ws)
{
    int i = blockIdx.x * 256 + threadIdx.x;
    if (i < 4096) {
        float N = (float)(Bn * L2O);
        float m = ws[S2S + i] / N;
        float v = ws[S2Q + i] / N - m * m;
        ws[S2M + i] = m; ws[S2I + i] = rsqrtf(v + 1e-5f);
    }
}

// ---------------- conv2 bn + pool -> q bf16 [c][b][o2*27+j] ----------------
__global__ void bn2_pool_kernel(const float* __restrict__ y2, const float* __restrict__ ws,
    const float* __restrict__ g, const float* __restrict__ be, unsigned short* __restrict__ q)
{
    long idx = (long)blockIdx.x * 256 + threadIdx.x;
    if (idx >= (long)Cn * Bn * C2O * L2P) return;
    int j = idx % L2P; long r = idx / L2P;
    int o2 = r % C2O; long r2 = r / C2O; int b = r2 % Bn; int c = r2 / Bn;
    int co = c * C2O + o2;
    float sc = ws[S2I + co] * g[co], sh = be[co] - ws[S2M + co] * sc;
    const float* yb = y2 + ((long)(c * Bn + b) * C2O + o2) * L2O + 2 * j;
    q[idx] = f2bf(fmaxf(sc * yb[0] + sh, sc * yb[1] + sh));
}

// ---------------- lin1 MFMA: per channel [64 x 1728(bf16)] @ [512 x 1728(fp32->bf16)]^T ----------------
__global__ __launch_bounds__(256) void lin1_mfma_kernel(const unsigned short* __restrict__ q,
    const float* __restrict__ w, const float* __restrict__ bias, float* __restrict__ cout_)
{
    int c = blockIdx.y;
    int n0 = blockIdx.x * 64;
    int tid = threadIdx.x, wv = tid >> 6, lane = tid & 63;
    int lx = lane & 15, g = lane >> 4;
    int wm = wv & 1, wn = wv >> 1;

    const unsigned short* a0 = q + (long)(c * 64 + wm * 32 + lx) * 1728 + g * 8;
    const float* w0 = w + ((long)c * 512 + n0 + wn * 32 + lx) * 1728 + g * 8;

    f32x4 acc[2][2] = {};
    for (int kstep = 0; kstep < 54; ++kstep) {
        short8 af[2];
        af[0] = *(const short8*)(a0 + kstep * 32);
        af[1] = *(const short8*)(a0 + 16 * 1728 + kstep * 32);
        short8 bf[2];
#pragma unroll
        for (int nb = 0; nb < 2; ++nb) {
            const float* wp = w0 + (long)nb * 16 * 1728 + kstep * 32;
            float4 x = *(const float4*)(wp);
            float4 y = *(const float4*)(wp + 4);
            bf[nb] = cvt8(x, y);
        }
#pragma unroll
        for (int ma = 0; ma < 2; ++ma)
#pragma unroll
            for (int nb = 0; nb < 2; ++nb)
                acc[ma][nb] = __builtin_amdgcn_mfma_f32_16x16x32_bf16(af[ma], bf[nb], acc[ma][nb], 0, 0, 0);
    }
#pragma unroll
    for (int ma = 0; ma < 2; ++ma)
#pragma unroll
        for (int nb = 0; nb < 2; ++nb) {
            int o = n0 + wn * 32 + nb * 16 + lx;
            float bia = bias[c * 512 + o];
#pragma unroll
            for (int r = 0; r < 4; ++r) {
                int b = wm * 32 + ma * 16 + g * 4 + r;
                cout_[((long)(c * 64 + b)) * 512 + o] = fmaxf(acc[ma][nb][r] + bia, 0.f);
            }
        }
}

// ---------------- gather x0[v][b][f] = cout[perm[v]][b][f] ----------------
__global__ void gather_x0_kernel(const float* __restrict__ cout_, const int* __restrict__ perm,
                                 float* __restrict__ x0)
{
    long idx = (long)blockIdx.x * 256 + threadIdx.x;
    if (idx < (long)Cn * Bn * FIN1) {
        int v = idx / (Bn * FIN1); long r = idx % (Bn * FIN1);
        x0[idx] = cout_[(long)perm[v] * Bn * FIN1 + r];
    }
}

// ---------------- chebyshev recursion: Y = Lr@X (sub=0) or Y = 2*Lr@X - Xp (fp32) ----------------
template<int V>
__global__ __launch_bounds__(256) void cheby_rec_kernel(const float* __restrict__ Lr,
    const float* __restrict__ X, const float* __restrict__ Xp, float* __restrict__ Y, int M, int sub)
{
    __shared__ float L[V * V];
    for (int i = threadIdx.x; i < V * V; i += 256) L[i] = Lr[i];
    __syncthreads();
    long m = (long)blockIdx.x * 256 + threadIdx.x;
    int v0 = blockIdx.y * 16;
    float acc[16] = {};
    for (int u = 0; u < V; ++u) {
        float x = X[(long)u * M + m];
#pragma unroll
        for (int i = 0; i < 16; ++i) acc[i] = fmaf(L[(v0 + i) * V + u], x, acc[i]);
    }
#pragma unroll
    for (int i = 0; i < 16; ++i) {
        long o = (long)(v0 + i) * M + m;
        Y[o] = sub ? (2.f * acc[i] - Xp[o]) : acc[i];
    }
}

// ---------------- cheby layer-1 output GEMM via MFMA ----------------
// out[b][v][o] = relu(sum_{kc,f} xk[kc][v][b][f] * W1R[kc][o][f] + bias[o]); M=4096, N=64, K=5*512
__global__ __launch_bounds__(256) void cheby1_mfma_kernel(const float* __restrict__ xk,
    const float* __restrict__ Wr, const float* __restrict__ bias, float* __restrict__ out)
{
    int m0 = blockIdx.x * 64;
    __shared__ unsigned short Bl[64 * 512];   // one kc slice, swizzled
    int tid = threadIdx.x, w = tid >> 6, lane = tid & 63;
    int lx = lane & 15, g = lane >> 4;
    int m = m0 + w * 16 + lx;
    int v = m & 63, b = m >> 6;

    f32x4 acc[4] = {};
    for (int kc = 0; kc < 5; ++kc) {
        __syncthreads();
        const float* wsrc = Wr + (long)kc * 64 * 512;
#pragma unroll
        for (int it = 0; it < 16; ++it) {
            int j = it * 256 + tid;
            int n = j >> 6, kb = j & 63;
            const float* sp = wsrc + n * 512 + kb * 8;
            float4 x = *(const float4*)(sp);
            float4 y = *(const float4*)(sp + 4);
            union { short8 v8; uint4 u4; } cvtd; cvtd.v8 = cvt8(x, y);
            int dst = (n * 1024 + kb * 16) ^ ((n & 7) << 4);
            *(uint4*)((char*)Bl + dst) = cvtd.u4;
        }
        __syncthreads();
        const float* ab = xk + ((long)(kc * 64 + v) * 64 + b) * 512 + g * 8;
        for (int kl = 0; kl < 16; ++kl) {
            float4 x = *(const float4*)(ab + kl * 32);
            float4 y = *(const float4*)(ab + kl * 32 + 4);
            short8 af = cvt8(x, y);
#pragma unroll
            for (int fi = 0; fi < 4; ++fi) {
                int n = fi * 16 + lx;
                int off = (n * 1024 + kl * 64 + g * 16) ^ ((n & 7) << 4);
                short8 bfrag = *(const short8*)((char*)Bl + off);
                acc[fi] = __builtin_amdgcn_mfma_f32_16x16x32_bf16(af, bfrag, acc[fi], 0, 0, 0);
            }
        }
    }
#pragma unroll
    for (int fi = 0; fi < 4; ++fi) {
        int o = fi * 16 + lx;
        float bia = bias[o];
#pragma unroll
        for (int r = 0; r < 4; ++r) {
            int mm = m0 + w * 16 + g * 4 + r;
            int vv = mm & 63, bb = mm >> 6;
            out[((long)(bb * 64 + vv)) * 64 + o] = fmaxf(acc[fi][r] + bia, 0.f);
        }
    }
}

// ---------------- cheby layer-2 output GEMM via MFMA ----------------
// out[b][v][o] = relu(sum xk[kc][v][b][f] * W2R[kc][o][f] + bias[o]); M=2048(v=32), N=128, K=5*64=320
__global__ __launch_bounds__(256) void cheby2_mfma_kernel(const float* __restrict__ xk,
    const float* __restrict__ Wr, const float* __restrict__ bias, float* __restrict__ out)
{
    int n0 = blockIdx.x * 64;
    int m0 = blockIdx.y * 64;
    __shared__ unsigned short Bl[64 * 320];   // full K for 64 n-rows, swizzled
    int tid = threadIdx.x, w = tid >> 6, lane = tid & 63;
    int lx = lane & 15, g = lane >> 4;

    // stage B: 2560 chunks of 8 bf16
#pragma unroll
    for (int it = 0; it < 10; ++it) {
        int j = it * 256 + tid;
        int n = j / 40, kb = j % 40;
        int kc = kb >> 3, f0 = (kb & 7) * 8;
        const float* sp = Wr + ((long)kc * 128 + n0 + n) * 64 + f0;
        float4 x = *(const float4*)(sp);
        float4 y = *(const float4*)(sp + 4);
        union { short8 v8; uint4 u4; } cvtd; cvtd.v8 = cvt8(x, y);
        int dst = (n * 640 + kb * 16) ^ ((n & 7) << 4);
        *(uint4*)((char*)Bl + dst) = cvtd.u4;
    }
    __syncthreads();

    int m = m0 + w * 16 + lx;
    int v = m & 31, b = m >> 5;

    f32x4 acc[4] = {};
    for (int kstep = 0; kstep < 10; ++kstep) {
        int k = kstep * 32 + g * 8;
        int kc = k >> 6, f = k & 63;
        const float* ap = xk + ((long)(kc * 32 + v) * 64 + b) * 64 + f;
        float4 x = *(const float4*)(ap);
        float4 y = *(const float4*)(ap + 4);
        short8 af = cvt8(x, y);
#pragma unroll
        for (int fi = 0; fi < 4; ++fi) {
            int n = fi * 16 + lx;
            int kb = kstep * 4 + g;
            int off = (n * 640 + kb * 16) ^ ((n & 7) << 4);
            short8 bfrag = *(const short8*)((char*)Bl + off);
            acc[fi] = __builtin_amdgcn_mfma_f32_16x16x32_bf16(af, bfrag, acc[fi], 0, 0, 0);
        }
    }
#pragma unroll
    for (int fi = 0; fi < 4; ++fi) {
        int o = n0 + fi * 16 + lx;
        float bia = bias[o];
#pragma unroll
        for (int r = 0; r < 4; ++r) {
            int mm = m0 + w * 16 + g * 4 + r;
            int vv = mm & 31, bb = mm >> 5;
            out[((long)(bb * 32 + vv)) * 128 + o] = fmaxf(acc[fi][r] + bia, 0.f);
        }
    }
}

// ---------------- generic fp32 tiled GEMM (kept for fc1) ----------------
__global__ __launch_bounds__(256) void gemm_tn_kernel(const float* __restrict__ A, const float* __restrict__ W,
    const float* __restrict__ bias, float* __restrict__ Cm,
    int M, int N, int K, long sA, long sW, long sC, long sB, int relu)
{
    int bz = blockIdx.z;
    A += (long)bz * sA; W += (long)bz * sW; Cm += (long)bz * sC; bias += (long)bz * sB;
    int m0 = blockIdx.y * 64, n0 = blockIdx.x * 64;
    __shared__ float As[32][68];
    __shared__ float Bs[32][68];
    int tid = threadIdx.x, tx = tid & 15, ty = tid >> 4;
    int lr = tid >> 3, lq = tid & 7;
    float acc[4][4] = {};
    for (int k0 = 0; k0 < K; k0 += 32) {
        float4 a0 = *(const float4*)&A[(long)(m0 + lr) * K + k0 + 4 * lq];
        float4 a1 = *(const float4*)&A[(long)(m0 + lr + 32) * K + k0 + 4 * lq];
        float4 w0 = *(const float4*)&W[(long)(n0 + lr) * K + k0 + 4 * lq];
        float4 w1v = *(const float4*)&W[(long)(n0 + lr + 32) * K + k0 + 4 * lq];
        __syncthreads();
        As[4 * lq + 0][lr] = a0.x; As[4 * lq + 1][lr] = a0.y; As[4 * lq + 2][lr] = a0.z; As[4 * lq + 3][lr] = a0.w;
        As[4 * lq + 0][lr + 32] = a1.x; As[4 * lq + 1][lr + 32] = a1.y; As[4 * lq + 2][lr + 32] = a1.z; As[4 * lq + 3][lr + 32] = a1.w;
        Bs[4 * lq + 0][lr] = w0.x; Bs[4 * lq + 1][lr] = w0.y; Bs[4 * lq + 2][lr] = w0.z; Bs[4 * lq + 3][lr] = w0.w;
        Bs[4 * lq + 0][lr + 32] = w1v.x; Bs[4 * lq + 1][lr + 32] = w1v.y; Bs[4 * lq + 2][lr + 32] = w1v.z; Bs[4 * lq + 3][lr + 32] = w1v.w;
        __syncthreads();
#pragma unroll
        for (int kk = 0; kk < 32; ++kk) {
            float a[4], bb[4];
#pragma unroll
            for (int i = 0; i < 4; ++i) a[i] = As[kk][4 * ty + i];
#pragma unroll
            for (int j = 0; j < 4; ++j) bb[j] = Bs[kk][4 * tx + j];
#pragma unroll
            for (int i = 0; i < 4; ++i)
#pragma unroll
                for (int j = 0; j < 4; ++j) acc[i][j] = fmaf(a[i], bb[j], acc[i][j]);
        }
    }
#pragma unroll
    for (int i = 0; i < 4; ++i) {
#pragma unroll
        for (int j = 0; j < 4; ++j) {
            float v = acc[i][j] + bias[n0 + 4 * tx + j];
            if (relu) v = fmaxf(v, 0.f);
            Cm[(long)(m0 + 4 * ty + i) * N + n0 + 4 * tx + j] = v;
        }
    }
}

// ---------------- graph BN + graph max-pool ----------------
template<int Fdim, int XOUT>
__global__ __launch_bounds__(256) void gbn_gpool_kernel(const float* __restrict__ y,
    const float* __restrict__ g, const float* __restrict__ be, float eps, int V, float* __restrict__ out)
{
    int j = blockIdx.x; int v0 = 2 * j;
    int tid = threadIdx.x;
    float s0 = 0.f, q0 = 0.f, s1 = 0.f, q1 = 0.f;
    int Ntot = Bn * Fdim;
    for (int idx = tid; idx < Ntot; idx += 256) {
        int b = idx / Fdim, f = idx % Fdim;
        float a = y[((long)b * V + v0) * Fdim + f];
        float c = y[((long)b * V + v0 + 1) * Fdim + f];
        s0 += a; q0 += a * a; s1 += c; q1 += c * c;
    }
    __shared__ float red[4][256];
    red[0][tid] = s0; red[1][tid] = q0; red[2][tid] = s1; red[3][tid] = q1;
    __syncthreads();
    for (int st = 128; st > 0; st >>= 1) {
        if (tid < st) {
#pragma unroll
            for (int r = 0; r < 4; ++r) red[r][tid] += red[r][tid + st];
        }
        __syncthreads();
    }
    float N = (float)Ntot;
    float m0 = red[0][0] / N, i0 = rsqrtf(red[1][0] / N - m0 * m0 + eps);
    float m1 = red[2][0] / N, i1 = rsqrtf(red[3][0] / N - m1 * m1 + eps);
    float sc0 = i0 * g[v0], sh0 = be[v0] - m0 * sc0;
    float sc1 = i1 * g[v0 + 1], sh1 = be[v0 + 1] - m1 * sc1;
    for (int idx = tid; idx < Ntot; idx += 256) {
        int b = idx / Fdim, f = idx % Fdim;
        float a = y[((long)b * V + v0) * Fdim + f];
        float c = y[((long)b * V + v0 + 1) * Fdim + f];
        float r = fmaxf(sc0 * a + sh0, sc1 * c + sh1);
        long oidx = XOUT ? ((long)j * Bn + b) * Fdim + f : ((long)b * (V / 2) + j) * Fdim + f;
        out[oidx] = r;
    }
}

// ---------------- fc2 ----------------
__global__ void fc2_kernel(const float* __restrict__ x, const float* __restrict__ w,
                           const float* __restrict__ bv, float* __restrict__ out)
{
    int tid = threadIdx.x;   // 128 threads
    int b = tid >> 1, o = tid & 1;
    float acc = bv[o];
    for (int f = 0; f < 512; ++f) acc = fmaf(x[b * 512 + f], w[o * 512 + f], acc);
    out[tid] = acc;
}

// ---------------- launch ----------------
extern "C" void kernel_launch(void* const* d_in, const int* in_sizes, int n_in,
                              void* d_out, int out_size, void* d_ws, size_t ws_size,
                              hipStream_t stream)
{
    const float* inp    = (const float*)d_in[0];
    const float* L0     = (const float*)d_in[2];
    const float* L1m    = (const float*)d_in[3];
    const int*   lmax0  = (const int*)d_in[4];
    const int*   lmax1  = (const int*)d_in[5];
    const int*   perm   = (const int*)d_in[6];
    const float* conv1_w = (const float*)d_in[8];
    const float* conv1_b = (const float*)d_in[9];
    const float* bn1_g  = (const float*)d_in[10];
    const float* bn1_b  = (const float*)d_in[11];
    const float* conv2_w = (const float*)d_in[12];
    const float* conv2_b = (const float*)d_in[13];
    const float* bn2_g  = (const float*)d_in[14];
    const float* bn2_b  = (const float*)d_in[15];
    const float* lin1_w = (const float*)d_in[16];
    const float* lin1_b = (const float*)d_in[17];
    const float* cl1_b  = (const float*)d_in[19];
    const float* gbn1_g = (const float*)d_in[20];
    const float* gbn1_b = (const float*)d_in[21];
    const float* cl2_b  = (const float*)d_in[23];
    const float* gbn2_g = (const float*)d_in[24];
    const float* gbn2_b = (const float*)d_in[25];
    const float* fc1_w  = (const float*)d_in[26];
    const float* fc1_b  = (const float*)d_in[27];
    const float* fc2_w  = (const float*)d_in[28];
    const float* fc2_b  = (const float*)d_in[29];
    const float* cl1_w  = (const float*)d_in[18];
    const float* cl2_w  = (const float*)d_in[22];
    float* ws  = (float*)d_ws;
    char*  wsb = (char*)d_ws;
    float* out = (float*)d_out;

    unsigned short* w2b = (unsigned short*)(wsb + W2B_B);
    unsigned short* p1b = (unsigned short*)(wsb + P1B_B);
    float*          y2  = (float*)(wsb + Y2_B);
    unsigned short* qb  = (unsigned short*)(wsb + QB_B);
    float*          co  = (float*)(wsb + CO_B);
    float*          xk  = (float*)(wsb + XK_B);
    float*          ch1 = (float*)(wsb + CH1_B);
    float*          x2k = (float*)(wsb + X2K_B);
    float*          ch2 = (float*)(wsb + CH2_B);
    float*          fci = (float*)(wsb + FCI_B);
    float*          fo1 = (float*)(wsb + FO1_B);
    float*          lr0 = (float*)(wsb + LR0_B);
    float*          lr1 = (float*)(wsb + LR1_B);
    float*          w1r = (float*)(wsb + W1R_B);
    float*          w2r = (float*)(wsb + W2R_B);

    // 0. prep: Lr + cheby repacks + conv2_w bf16
    prep_kernel<<<9013, 256, 0, stream>>>(L0, L1m, lmax0, lmax1, cl1_w, cl2_w, conv2_w, ws, w2b);

    // 1. conv1 stats, then recompute+bn+pool -> p1b (bf16)
    conv1_stats_kernel<<<2048, 256, 0, stream>>>(inp, conv1_w, conv1_b, ws);
    conv1_bnpool_kernel<<<2048, 256, 0, stream>>>(inp, conv1_w, conv1_b, bn1_g, bn1_b, ws, p1b);

    // 2. conv2 MFMA (+relu+stats) -> y2 fp32, stats finalize, bn+pool -> q bf16
    hipMemsetAsync(ws + S2S, 0, 8192 * sizeof(float), stream);
    conv2_mfma_kernel<<<dim3(55, 64), 256, 0, stream>>>(p1b, w2b, conv2_b, y2, ws + S2S, ws + S2Q);
    stats2_fin_kernel<<<16, 256, 0, stream>>>(ws);
    bn2_pool_kernel<<<27648, 256, 0, stream>>>(y2, ws, bn2_g, bn2_b, qb);

    // 3. lin1 MFMA (in-register fp32->bf16 weight cvt) -> cout fp32
    lin1_mfma_kernel<<<dim3(8, 64), 256, 0, stream>>>(qb, lin1_w, lin1_b, co);

    // 4. cheby layer 1: gather + fp32 recursion + MFMA output GEMM
    const long XKS = (long)Cn * Bn * FIN1;   // 2097152
    gather_x0_kernel<<<8192, 256, 0, stream>>>(co, perm, xk);
    cheby_rec_kernel<64><<<dim3(128, 4), 256, 0, stream>>>(lr0, xk,           nullptr,      xk + XKS,     32768, 0);
    cheby_rec_kernel<64><<<dim3(128, 4), 256, 0, stream>>>(lr0, xk + XKS,     xk,           xk + 2 * XKS, 32768, 1);
    cheby_rec_kernel<64><<<dim3(128, 4), 256, 0, stream>>>(lr0, xk + 2 * XKS, xk + XKS,     xk + 3 * XKS, 32768, 1);
    cheby_rec_kernel<64><<<dim3(128, 4), 256, 0, stream>>>(lr0, xk + 3 * XKS, xk + 2 * XKS, xk + 4 * XKS, 32768, 1);
    cheby1_mfma_kernel<<<64, 256, 0, stream>>>(xk, w1r, cl1_b, ch1);

    // 5. gbn1 + gpool1 -> x2k[0] in [v'][b][f] layout
    gbn_gpool_kernel<64, 1><<<32, 256, 0, stream>>>(ch1, gbn1_g, gbn1_b, 64.0f, 64, x2k);

    // 6. cheby layer 2
    const long X2S = (long)32 * Bn * 64;     // 131072
    cheby_rec_kernel<32><<<dim3(16, 2), 256, 0, stream>>>(lr1, x2k,           nullptr,       x2k + X2S,     4096, 0);
    cheby_rec_kernel<32><<<dim3(16, 2), 256, 0, stream>>>(lr1, x2k + X2S,     x2k,           x2k + 2 * X2S, 4096, 1);
    cheby_rec_kernel<32><<<dim3(16, 2), 256, 0, stream>>>(lr1, x2k + 2 * X2S, x2k + X2S,     x2k + 3 * X2S, 4096, 1);
    cheby_rec_kernel<32><<<dim3(16, 2), 256, 0, stream>>>(lr1, x2k + 3 * X2S, x2k + 2 * X2S, x2k + 4 * X2S, 4096, 1);
    cheby2_mfma_kernel<<<dim3(2, 32), 256, 0, stream>>>(x2k, w2r, cl2_b, ch2);

    // 7. gbn2 + gpool2 -> fc input [b][2048]
    gbn_gpool_kernel<128, 0><<<16, 256, 0, stream>>>(ch2, gbn2_g, gbn2_b, 128.0f, 32, fci);

    // 8. fc1 (+relu) fp32 and fc2
    gemm_tn_kernel<<<dim3(8, 1, 1), 256, 0, stream>>>(fci, fc1_w, fc1_b, fo1,
        64, 512, 2048, 0, 0, 0, 0, 1);
    fc2_kernel<<<1, 128, 0, stream>>>(fo1, fc2_w, fc2_b, out);
}

// Round 3
// 458.544 us; speedup vs baseline: 2.0383x; 1.2296x over previous
//
#include <hip/hip_runtime.h>
#include <hip/hip_bf16.h>

typedef __attribute__((ext_vector_type(8))) short short8;
typedef __attribute__((ext_vector_type(4))) float f32x4;

// ---------------- constants ----------------
namespace {
constexpr int Bn  = 64;    // batch
constexpr int Cn  = 64;    // sensor channels / graph nodes
constexpr int DIN = 512;
constexpr int C1O = 32, C2O = 64;
constexpr int L1O = 249, L1P = 124;
constexpr int L2O = 55,  L2P = 27;
constexpr int FIN1 = 512;
constexpr int LIN1K = C2O * L2P;      // 1728

// stats floats
constexpr long S1M = 0;          // 2048
constexpr long S1I = 2048;       // 2048
constexpr long S2S = 4096;       // 4096 (zeroed by prep)
constexpr long S2Q = 8192;       // 4096 (zeroed by prep)

// byte offsets
constexpr long LR0_B  = 65536;       // 4096 f   -> 81920
constexpr long LR1_B  = 81920;       // 1024 f   -> 86016
constexpr long W1RB_B = 86016;       // 163840 bf16 -> 413696
constexpr long W2RB_B = 413696;      // 40960 bf16  -> 495616
constexpr long W2B_B  = 495616;      // 2097152 bf16 -> 4689920
constexpr long P1B_B  = 4689920;     // 16252928 bf16 -> 37195776
constexpr long Y2_B   = 37195776;    // 14417920 f   -> 94867456
constexpr long QB_B   = 94867456;    // 7077888 bf16 -> 109023232
constexpr long CO_B   = 109023232;   // 2097152 f    -> 117411840
constexpr long XK_B   = 4689920;     // alias p1b/y2 (dead): 5*2097152 f -> 46632960
constexpr long CH1_B  = 117411840;   // 262144 f
constexpr long X2K_B  = 118460416;   // 131072 f (x2k0 slab only)
constexpr long CH2_B  = 118984704;   // 262144 f
constexpr long FCI_B  = 120033280;   // 131072 bf16
constexpr long FO1_B  = 120295424;   // 32768 f
}

__device__ __forceinline__ unsigned short f2bf(float f) {
    union { float f; unsigned u; } v; v.f = f;
    unsigned r = v.u + 0x7FFFu + ((v.u >> 16) & 1u);
    return (unsigned short)(r >> 16);
}

__device__ __forceinline__ short8 cvt8(float4 a, float4 b) {
    float f[8] = {a.x, a.y, a.z, a.w, b.x, b.y, b.z, b.w};
    union { unsigned short s[8]; short8 v; } r;
#pragma unroll
    for (int i = 0; i < 8; ++i) r.s[i] = f2bf(f[i]);
    return r.v;
}

// ---------------- prep: zero stats + Lr + cheby bf16 repacks + conv2_w bf16 ----------------
__global__ void prep_kernel(const float* __restrict__ L0, const float* __restrict__ L1m,
                            const int* __restrict__ lmax0, const int* __restrict__ lmax1,
                            const float* __restrict__ cl1w, const float* __restrict__ cl2w,
                            const float* __restrict__ conv2w, float* __restrict__ ws)
{
    long idx = (long)blockIdx.x * 256 + threadIdx.x;
    float inv0 = 2.0f / (float)lmax0[0];
    float inv1 = 2.0f / (float)lmax1[0];
    char* wsb = (char*)ws;
    float* LR0p = (float*)(wsb + LR0_B);
    float* LR1p = (float*)(wsb + LR1_B);
    unsigned short* W1Rp = (unsigned short*)(wsb + W1RB_B);
    unsigned short* W2Rp = (unsigned short*)(wsb + W2RB_B);
    unsigned short* w2b  = (unsigned short*)(wsb + W2B_B);
    if (idx < 8192) {
        ws[S2S + idx] = 0.f;
    } else if (idx < 8192 + 4096) {
        long t = idx - 8192; int i = t / 64, j = t % 64;
        LR0p[t] = L0[t] * inv0 - (i == j ? 1.0f : 0.0f);
    } else if (idx < 8192 + 4096 + 1024) {
        long t = idx - 8192 - 4096; int i = t / 32, j = t % 32;
        LR1p[t] = L1m[t] * inv1 - (i == j ? 1.0f : 0.0f);
    } else if (idx < 8192 + 4096 + 1024 + 163840) {
        long t = idx - 8192 - 4096 - 1024;
        int k = t / 32768; int r = t % 32768; int o = r / 512, f = r % 512;
        W1Rp[t] = f2bf(cl1w[o * 2560 + f * 5 + k]);
    } else if (idx < 8192 + 4096 + 1024 + 163840 + 40960) {
        long t = idx - 8192 - 4096 - 1024 - 163840;
        int k = t / 8192; int r = t % 8192; int o = r / 64, f = r % 64;
        W2Rp[t] = f2bf(cl2w[o * 320 + f * 5 + k]);
    } else if (idx < 8192 + 4096 + 1024 + 163840 + 40960 + 2097152) {
        long t = idx - 8192 - 4096 - 1024 - 163840 - 40960;
        w2b[t] = f2bf(conv2w[t]);
    }
}

// ---------------- conv1 stats: one block per (c,o), float4 loads, 8 outputs/group ----------------
__global__ __launch_bounds__(256) void conv1_stats_kernel(const float* __restrict__ inp,
    const float* __restrict__ w1, const float* __restrict__ b1, float* __restrict__ ws)
{
    int co = blockIdx.x; int c = co >> 5;
    float w[16];
#pragma unroll
    for (int t = 0; t < 16; ++t) w[t] = w1[co * 16 + t];
    float bias = b1[co];
    float s = 0.f, q = 0.f;
    for (int it = 0; it < 8; ++it) {
        int idx = it * 256 + threadIdx.x;      // 0..2047
        int b = idx >> 5, grp = idx & 31;
        const float* ip = inp + ((b << 6) + c) * 512 + grp * 16;
        float x[32];
        if (grp < 31) {
#pragma unroll
            for (int h = 0; h < 8; ++h) *(float4*)&x[h * 4] = *(const float4*)(ip + h * 4);
#pragma unroll
            for (int j = 0; j < 8; ++j) {
                float a = bias;
#pragma unroll
                for (int t = 0; t < 16; ++t) a = fmaf(x[2 * j + t], w[t], a);
                a = fmaxf(a, 0.f);
                s += a; q += a * a;
            }
        } else {
#pragma unroll
            for (int h = 0; h < 4; ++h) *(float4*)&x[h * 4] = *(const float4*)(ip + h * 4);
            float a = bias;
#pragma unroll
            for (int t = 0; t < 16; ++t) a = fmaf(x[t], w[t], a);
            a = fmaxf(a, 0.f);
            s += a; q += a * a;
        }
    }
    __shared__ float rs[256], rq[256];
    rs[threadIdx.x] = s; rq[threadIdx.x] = q;
    __syncthreads();
    for (int st = 128; st > 0; st >>= 1) {
        if (threadIdx.x < st) { rs[threadIdx.x] += rs[threadIdx.x + st]; rq[threadIdx.x] += rq[threadIdx.x + st]; }
        __syncthreads();
    }
    if (threadIdx.x == 0) {
        float N = (float)(Bn * L1O);
        float m = rs[0] / N, v = rq[0] / N - m * m;
        ws[S1M + co] = m; ws[S1I + co] = rsqrtf(v + 1e-5f);
    }
}

// ---------------- conv1 recompute + bn + maxpool -> p1b bf16 [c][b][o][124], 4 outs/group ----------------
__global__ __launch_bounds__(256) void conv1_bnpool_kernel(const float* __restrict__ inp,
    const float* __restrict__ w1, const float* __restrict__ b1,
    const float* __restrict__ g, const float* __restrict__ be,
    const float* __restrict__ ws, unsigned short* __restrict__ p1)
{
    int co = blockIdx.x; int c = co >> 5, o = co & 31;
    float w[16];
#pragma unroll
    for (int t = 0; t < 16; ++t) w[t] = w1[co * 16 + t];
    float bias = b1[co];
    float m = ws[S1M + co], inv = ws[S1I + co];
    float sc = inv * g[co], sh = be[co] - m * sc;
    for (int it = 0; it < 8; ++it) {
        int idx = it * 256 + threadIdx.x;
        if (idx >= 64 * 31) continue;          // 1984 groups
        int b = idx / 31, jg = idx % 31;
        const float* ip = inp + ((b << 6) + c) * 512 + jg * 16;
        float x[32];
#pragma unroll
        for (int h = 0; h < 8; ++h) *(float4*)&x[h * 4] = *(const float4*)(ip + h * 4);
        unsigned short* op = p1 + ((long)((c << 6) + b) * C1O + o) * 124 + jg * 4;
#pragma unroll
        for (int jj = 0; jj < 4; ++jj) {
            float a0 = bias, a1 = bias;
#pragma unroll
            for (int t = 0; t < 16; ++t) {
                a0 = fmaf(x[4 * jj + t], w[t], a0);
                a1 = fmaf(x[4 * jj + 2 + t], w[t], a1);
            }
            float r0 = fmaxf(a0, 0.f) * sc + sh;
            float r1 = fmaxf(a1, 0.f) * sc + sh;
            op[jj] = f2bf(fmaxf(r0, r1));
        }
    }
}

// ---------------- conv2 MFMA GEMM + relu + stats; y2 layout [c][b][l][o2] ----------------
__global__ __launch_bounds__(256) void conv2_mfma_kernel(const unsigned short* __restrict__ p1b,
    const unsigned short* __restrict__ w2b, const float* __restrict__ b2,
    float* __restrict__ y2, float* __restrict__ s2s, float* __restrict__ s2q)
{
    int c = blockIdx.y;
    int m0 = blockIdx.x * 64;
    __shared__ unsigned short Bl[64 * 512];
    __shared__ float red[2][4][64];
    int tid = threadIdx.x;
    int w = tid >> 6, lane = tid & 63;
    int lx = lane & 15, g = lane >> 4;

    const unsigned short* wsrc = w2b + (long)c * 64 * 512;
#pragma unroll
    for (int it = 0; it < 16; ++it) {
        int j = it * 256 + tid;
        int n = j >> 6, kb = j & 63;
        uint4 val = *(const uint4*)(wsrc + n * 512 + kb * 8);
        int dst = (n * 1024 + kb * 16) ^ ((n & 7) << 4);
        *(uint4*)((char*)Bl + dst) = val;
    }
    __syncthreads();

    int m = m0 + w * 16 + lx;
    int b = m / 55, lpos = m % 55;
    const unsigned short* abase = p1b + ((long)(c * 64 + b) * 32) * 124 + 2 * lpos + (g & 1) * 8;
    int cio = g >> 1;

    f32x4 acc[4] = {};
    for (int kstep = 0; kstep < 16; ++kstep) {
        const unsigned short* ap = abase + (kstep * 2 + cio) * 124;
        union { unsigned u[4]; short8 v; } af;
        af.u[0] = *(const unsigned*)(ap + 0);
        af.u[1] = *(const unsigned*)(ap + 2);
        af.u[2] = *(const unsigned*)(ap + 4);
        af.u[3] = *(const unsigned*)(ap + 6);
#pragma unroll
        for (int fi = 0; fi < 4; ++fi) {
            int n = fi * 16 + lx;
            int off = (n * 1024 + kstep * 64 + g * 16) ^ ((n & 7) << 4);
            short8 bfrag = *(const short8*)((char*)Bl + off);
            acc[fi] = __builtin_amdgcn_mfma_f32_16x16x32_bf16(af.v, bfrag, acc[fi], 0, 0, 0);
        }
    }

    float cs[4] = {}, cq[4] = {};
#pragma unroll
    for (int fi = 0; fi < 4; ++fi) {
        int o2 = fi * 16 + lx;
        float bia = b2[c * 64 + o2];
#pragma unroll
        for (int r = 0; r < 4; ++r) {
            int mm = m0 + w * 16 + g * 4 + r;
            int bb = mm / 55, ll = mm % 55;
            float y = fmaxf(acc[fi][r] + bia, 0.f);
            y2[((long)(c * 64 + bb) * 55 + ll) * 64 + o2] = y;   // o2 contiguous
            cs[fi] += y; cq[fi] += y * y;
        }
    }
#pragma unroll
    for (int fi = 0; fi < 4; ++fi) {
        cs[fi] += __shfl_xor(cs[fi], 16); cs[fi] += __shfl_xor(cs[fi], 32);
        cq[fi] += __shfl_xor(cq[fi], 16); cq[fi] += __shfl_xor(cq[fi], 32);
    }
    if (g == 0) {
#pragma unroll
        for (int fi = 0; fi < 4; ++fi) { red[0][w][fi * 16 + lx] = cs[fi]; red[1][w][fi * 16 + lx] = cq[fi]; }
    }
    __syncthreads();
    if (tid < 64) {
        float ss = red[0][0][tid] + red[0][1][tid] + red[0][2][tid] + red[0][3][tid];
        float qq = red[1][0][tid] + red[1][1][tid] + red[1][2][tid] + red[1][3][tid];
        atomicAdd(&s2s[c * 64 + tid], ss);
        atomicAdd(&s2q[c * 64 + tid], qq);
    }
}

// ---------------- conv2 bn + pool -> q bf16 [c][b][o2*27+j]; stats finalize inline ----------------
__global__ void bn2_pool_kernel(const float* __restrict__ y2, const float* __restrict__ ws,
    const float* __restrict__ g, const float* __restrict__ be, unsigned short* __restrict__ q)
{
    long idx = (long)blockIdx.x * 256 + threadIdx.x;
    if (idx >= (long)Cn * Bn * C2O * L2P) return;
    int o2 = idx & 63; long r = idx >> 6;
    int j = r % 27; long r2 = r / 27;
    int b = r2 & 63; int c = r2 >> 6;
    int co = c * 64 + o2;
    float N = (float)(Bn * L2O);
    float m = ws[S2S + co] / N;
    float inv = rsqrtf(ws[S2Q + co] / N - m * m + 1e-5f);
    float sc = inv * g[co], sh = be[co] - m * sc;
    const float* yb = y2 + ((long)(c * 64 + b) * 55 + 2 * j) * 64 + o2;
    float v = fmaxf(sc * yb[0] + sh, sc * yb[64] + sh);
    q[((long)(c * 64 + b) * 64 + o2) * 27 + j] = f2bf(v);
}

// ---------------- generic MFMA GEMM: C[64,Ntot] = relu(A_bf16[64,K] @ W_fp32[Ntot,K]^T + bias) ----------------
__global__ __launch_bounds__(256) void gemm_a16w32_kernel(const unsigned short* __restrict__ A,
    const float* __restrict__ W, const float* __restrict__ bias, float* __restrict__ C,
    int K, int Ntot, long sA, long sW, long sB, long sC)
{
    int c = blockIdx.y;
    A += (long)c * sA; W += (long)c * sW; bias += (long)c * sB; C += (long)c * sC;
    int n0 = blockIdx.x * 64;
    int tid = threadIdx.x, wv = tid >> 6, lane = tid & 63;
    int lx = lane & 15, g = lane >> 4;
    int wm = wv & 1, wn = wv >> 1;

    const unsigned short* a0 = A + (long)(wm * 32 + lx) * K + g * 8;
    const float* w0 = W + (long)(n0 + wn * 32 + lx) * K + g * 8;
    int ksteps = K >> 5;

    f32x4 acc[2][2] = {};
    for (int kstep = 0; kstep < ksteps; ++kstep) {
        short8 af[2];
        af[0] = *(const short8*)(a0 + kstep * 32);
        af[1] = *(const short8*)(a0 + (long)16 * K + kstep * 32);
        short8 bf[2];
#pragma unroll
        for (int nb = 0; nb < 2; ++nb) {
            const float* wp = w0 + (long)nb * 16 * K + kstep * 32;
            float4 x = *(const float4*)(wp);
            float4 y = *(const float4*)(wp + 4);
            bf[nb] = cvt8(x, y);
        }
#pragma unroll
        for (int ma = 0; ma < 2; ++ma)
#pragma unroll
            for (int nb = 0; nb < 2; ++nb)
                acc[ma][nb] = __builtin_amdgcn_mfma_f32_16x16x32_bf16(af[ma], bf[nb], acc[ma][nb], 0, 0, 0);
    }
#pragma unroll
    for (int ma = 0; ma < 2; ++ma)
#pragma unroll
        for (int nb = 0; nb < 2; ++nb) {
            int o = n0 + wn * 32 + nb * 16 + lx;
            float bia = bias[o];
#pragma unroll
            for (int r = 0; r < 4; ++r) {
                int b = wm * 32 + ma * 16 + g * 4 + r;
                C[(long)b * Ntot + o] = fmaxf(acc[ma][nb][r] + bia, 0.f);
            }
        }
}

// ---------------- chebyshev recursion V=64 (fp32), optional perm-gather + x0 write-through ----------------
__global__ __launch_bounds__(256) void cheby_rec64_kernel(const float* __restrict__ Lr,
    const float* __restrict__ Xsrc, const int* __restrict__ perm,
    const float* __restrict__ Xp, float* __restrict__ Y, float* __restrict__ X0out, int sub)
{
    __shared__ float L[64 * 64];
    for (int i = threadIdx.x; i < 4096; i += 256) L[i] = Lr[i];
    __syncthreads();
    int col = (blockIdx.x * 32 + (threadIdx.x & 31)) * 4;   // M = 32768
    int v0 = (threadIdx.x >> 5) * 8;
    float acc[8][4] = {};
    for (int u = 0; u < 64; ++u) {
        int row = perm ? perm[u] : u;
        float4 x = *(const float4*)&Xsrc[(long)row * 32768 + col];
        if (X0out && v0 == 0) *(float4*)&X0out[(long)u * 32768 + col] = x;
#pragma unroll
        for (int i = 0; i < 8; ++i) {
            float l = L[(v0 + i) * 64 + u];
            acc[i][0] = fmaf(l, x.x, acc[i][0]);
            acc[i][1] = fmaf(l, x.y, acc[i][1]);
            acc[i][2] = fmaf(l, x.z, acc[i][2]);
            acc[i][3] = fmaf(l, x.w, acc[i][3]);
        }
    }
#pragma unroll
    for (int i = 0; i < 8; ++i) {
        long o = (long)(v0 + i) * 32768 + col;
        float4 r;
        if (sub) {
            float4 p = *(const float4*)&Xp[o];
            r.x = 2.f * acc[i][0] - p.x; r.y = 2.f * acc[i][1] - p.y;
            r.z = 2.f * acc[i][2] - p.z; r.w = 2.f * acc[i][3] - p.w;
        } else {
            r.x = acc[i][0]; r.y = acc[i][1]; r.z = acc[i][2]; r.w = acc[i][3];
        }
        *(float4*)&Y[o] = r;
    }
}

// ---------------- cheby layer-1 output GEMM, M-tile 16, bf16 weights ----------------
// out[b][v][o] = relu(sum_{kc,f} xk[kc][v][b][f] * W1RB[kc][o][f] + bias[o]); M=4096,N=64,K=5*512
__global__ __launch_bounds__(256) void cheby1_mfma_kernel(const float* __restrict__ xk,
    const unsigned short* __restrict__ w1rb, const float* __restrict__ bias, float* __restrict__ out)
{
    int m0 = blockIdx.x * 16;
    __shared__ unsigned short Bl[64 * 512];
    int tid = threadIdx.x, wv = tid >> 6, lane = tid & 63;
    int lx = lane & 15, g = lane >> 4;
    int m = m0 + lx;
    int v = m & 63, b = m >> 6;

    f32x4 acc = {};
    for (int kc = 0; kc < 5; ++kc) {
        __syncthreads();
#pragma unroll
        for (int it = 0; it < 16; ++it) {
            int j = it * 256 + tid;
            int n = j >> 6, kb = j & 63;
            uint4 val = *(const uint4*)(w1rb + (long)kc * 32768 + n * 512 + kb * 8);
            int dst = (n * 1024 + kb * 16) ^ ((n & 7) << 4);
            *(uint4*)((char*)Bl + dst) = val;
        }
        __syncthreads();
        const float* ab = xk + ((long)(kc * 64 + v) * 64 + b) * 512 + g * 8;
        for (int kl = 0; kl < 16; ++kl) {
            float4 x = *(const float4*)(ab + kl * 32);
            float4 y = *(const float4*)(ab + kl * 32 + 4);
            short8 af = cvt8(x, y);
            int n = wv * 16 + lx;
            int off = (n * 1024 + kl * 64 + g * 16) ^ ((n & 7) << 4);
            short8 bfrag = *(const short8*)((char*)Bl + off);
            acc = __builtin_amdgcn_mfma_f32_16x16x32_bf16(af, bfrag, acc, 0, 0, 0);
        }
    }
    int o = wv * 16 + lx;
    float bia = bias[o];
#pragma unroll
    for (int r = 0; r < 4; ++r) {
        int mm = m0 + g * 4 + r;
        int vv = mm & 63, bb = mm >> 6;
        out[((long)(bb * 64 + vv)) * 64 + o] = fmaxf(acc[r] + bia, 0.f);
    }
}

// ---------------- graph BN + graph max-pool (fp32 out, cheby layout) ----------------
template<int Fdim, int XOUT>
__global__ __launch_bounds__(256) void gbn_gpool_kernel(const float* __restrict__ y,
    const float* __restrict__ g, const float* __restrict__ be, float eps, int V, float* __restrict__ out)
{
    int j = blockIdx.x; int v0 = 2 * j;
    int tid = threadIdx.x;
    float s0 = 0.f, q0 = 0.f, s1 = 0.f, q1 = 0.f;
    int Ntot = Bn * Fdim;
    for (int idx = tid; idx < Ntot; idx += 256) {
        int b = idx / Fdim, f = idx % Fdim;
        float a = y[((long)b * V + v0) * Fdim + f];
        float c = y[((long)b * V + v0 + 1) * Fdim + f];
        s0 += a; q0 += a * a; s1 += c; q1 += c * c;
    }
    __shared__ float red[4][256];
    red[0][tid] = s0; red[1][tid] = q0; red[2][tid] = s1; red[3][tid] = q1;
    __syncthreads();
    for (int st = 128; st > 0; st >>= 1) {
        if (tid < st) {
#pragma unroll
            for (int r = 0; r < 4; ++r) red[r][tid] += red[r][tid + st];
        }
        __syncthreads();
    }
    float N = (float)Ntot;
    float m0 = red[0][0] / N, i0 = rsqrtf(red[1][0] / N - m0 * m0 + eps);
    float m1 = red[2][0] / N, i1 = rsqrtf(red[3][0] / N - m1 * m1 + eps);
    float sc0 = i0 * g[v0], sh0 = be[v0] - m0 * sc0;
    float sc1 = i1 * g[v0 + 1], sh1 = be[v0 + 1] - m1 * sc1;
    for (int idx = tid; idx < Ntot; idx += 256) {
        int b = idx / Fdim, f = idx % Fdim;
        float a = y[((long)b * V + v0) * Fdim + f];
        float c = y[((long)b * V + v0 + 1) * Fdim + f];
        float r = fmaxf(sc0 * a + sh0, sc1 * c + sh1);
        long oidx = XOUT ? ((long)j * Bn + b) * Fdim + f : ((long)b * (V / 2) + j) * Fdim + f;
        out[oidx] = r;
    }
}

// ---------------- gbn2 + gpool2, bf16 out [b][j*128+f] ----------------
__global__ __launch_bounds__(256) void gbn2_bf16_kernel(const float* __restrict__ y,
    const float* __restrict__ g, const float* __restrict__ be, unsigned short* __restrict__ out)
{
    constexpr int Fdim = 128; constexpr int V = 32;
    int j = blockIdx.x; int v0 = 2 * j;
    int tid = threadIdx.x;
    float s0 = 0.f, q0 = 0.f, s1 = 0.f, q1 = 0.f;
    int Ntot = Bn * Fdim;
    for (int idx = tid; idx < Ntot; idx += 256) {
        int b = idx / Fdim, f = idx % Fdim;
        float a = y[((long)b * V + v0) * Fdim + f];
        float c = y[((long)b * V + v0 + 1) * Fdim + f];
        s0 += a; q0 += a * a; s1 += c; q1 += c * c;
    }
    __shared__ float red[4][256];
    red[0][tid] = s0; red[1][tid] = q0; red[2][tid] = s1; red[3][tid] = q1;
    __syncthreads();
    for (int st = 128; st > 0; st >>= 1) {
        if (tid < st) {
#pragma unroll
            for (int r = 0; r < 4; ++r) red[r][tid] += red[r][tid + st];
        }
        __syncthreads();
    }
    float N = (float)Ntot;
    float m0 = red[0][0] / N, i0 = rsqrtf(red[1][0] / N - m0 * m0 + 128.0f);
    float m1 = red[2][0] / N, i1 = rsqrtf(red[3][0] / N - m1 * m1 + 128.0f);
    float sc0 = i0 * g[v0], sh0 = be[v0] - m0 * sc0;
    float sc1 = i1 * g[v0 + 1], sh1 = be[v0 + 1] - m1 * sc1;
    for (int idx = tid; idx < Ntot; idx += 256) {
        int b = idx / Fdim, f = idx % Fdim;
        float a = y[((long)b * V + v0) * Fdim + f];
        float c = y[((long)b * V + v0 + 1) * Fdim + f];
        float r = fmaxf(sc0 * a + sh0, sc1 * c + sh1);
        out[((long)b * 16 + j) * Fdim + f] = f2bf(r);
    }
}

// ---------------- fused layer 2: cheby recursion (LDS) + MFMA GEMM, one block per b ----------------
// in x2k0[v][b][f] (V=32,F=64); out ch2[b][v][o] (O=128) with relu
__global__ __launch_bounds__(256) void layer2_kernel(const float* __restrict__ x2k0,
    const float* __restrict__ Lr1, const unsigned short* __restrict__ w2rb,
    const float* __restrict__ bias, float* __restrict__ out)
{
    int b = blockIdx.x;
    __shared__ float xs[5][32][72];             // padded rows
    __shared__ unsigned short wsl[128 * 320];   // swizzled rows of 640B
    int tid = threadIdx.x;

    // stage W: [kc][128 o][64 f] -> wsl[o][kc*64+f]
#pragma unroll
    for (int it = 0; it < 20; ++it) {
        int j = it * 256 + tid;                 // < 5120
        int o = j / 40, kb = j % 40;
        uint4 val = *(const uint4*)(w2rb + ((long)(kb >> 3) * 128 + o) * 64 + (kb & 7) * 8);
        int dst = (o * 640 + kb * 16) ^ ((o & 7) << 4);
        *(uint4*)((char*)wsl + dst) = val;
    }

    int v = tid & 31, fg = tid >> 5;            // fg 0..7
    float lrow[32];
#pragma unroll
    for (int u = 0; u < 32; ++u) lrow[u] = Lr1[v * 32 + u];

    {
        const float* sp = x2k0 + ((long)v * 64 + b) * 64 + fg * 8;
        float4 a = *(const float4*)sp;
        float4 c = *(const float4*)(sp + 4);
        *(float4*)&xs[0][v][fg * 8] = a;
        *(float4*)&xs[0][v][fg * 8 + 4] = c;
    }
    __syncthreads();

    for (int k = 1; k < 5; ++k) {
        float acc[8] = {};
#pragma unroll
        for (int u = 0; u < 32; ++u) {
            float4 xa = *(const float4*)&xs[k - 1][u][fg * 8];
            float4 xb = *(const float4*)&xs[k - 1][u][fg * 8 + 4];
            float l = lrow[u];
            acc[0] = fmaf(l, xa.x, acc[0]); acc[1] = fmaf(l, xa.y, acc[1]);
            acc[2] = fmaf(l, xa.z, acc[2]); acc[3] = fmaf(l, xa.w, acc[3]);
            acc[4] = fmaf(l, xb.x, acc[4]); acc[5] = fmaf(l, xb.y, acc[5]);
            acc[6] = fmaf(l, xb.z, acc[6]); acc[7] = fmaf(l, xb.w, acc[7]);
        }
        float4 ra, rb;
        if (k >= 2) {
            float4 pa = *(const float4*)&xs[k - 2][v][fg * 8];
            float4 pb = *(const float4*)&xs[k - 2][v][fg * 8 + 4];
            ra.x = 2.f * acc[0] - pa.x; ra.y = 2.f * acc[1] - pa.y;
            ra.z = 2.f * acc[2] - pa.z; ra.w = 2.f * acc[3] - pa.w;
            rb.x = 2.f * acc[4] - pb.x; rb.y = 2.f * acc[5] - pb.y;
            rb.z = 2.f * acc[6] - pb.z; rb.w = 2.f * acc[7] - pb.w;
        } else {
            ra.x = acc[0]; ra.y = acc[1]; ra.z = acc[2]; ra.w = acc[3];
            rb.x = acc[4]; rb.y = acc[5]; rb.z = acc[6]; rb.w = acc[7];
        }
        *(float4*)&xs[k][v][fg * 8] = ra;
        *(float4*)&xs[k][v][fg * 8 + 4] = rb;
        __syncthreads();
    }

    // GEMM: M=32 (v), N=128 (o), K=320
    int wv = tid >> 6, lane = tid & 63;
    int lx = lane & 15, g = lane >> 4;
    f32x4 acc2[2][2] = {};
    for (int kstep = 0; kstep < 10; ++kstep) {
        int k = kstep * 32 + g * 8;
        int kc = k >> 6, f = k & 63;
        short8 af[2];
#pragma unroll
        for (int ma = 0; ma < 2; ++ma) {
            int vv = ma * 16 + lx;
            float4 xa = *(const float4*)&xs[kc][vv][f];
            float4 xb = *(const float4*)&xs[kc][vv][f + 4];
            af[ma] = cvt8(xa, xb);
        }
#pragma unroll
        for (int nb = 0; nb < 2; ++nb) {
            int o = wv * 32 + nb * 16 + lx;
            int kb = kstep * 4 + g;
            int off = (o * 640 + kb * 16) ^ ((o & 7) << 4);
            short8 bf = *(const short8*)((char*)wsl + off);
#pragma unroll
            for (int ma = 0; ma < 2; ++ma)
                acc2[ma][nb] = __builtin_amdgcn_mfma_f32_16x16x32_bf16(af[ma], bf, acc2[ma][nb], 0, 0, 0);
        }
    }
#pragma unroll
    for (int ma = 0; ma < 2; ++ma)
#pragma unroll
        for (int nb = 0; nb < 2; ++nb) {
            int o = wv * 32 + nb * 16 + lx;
            float bia = bias[o];
#pragma unroll
            for (int r = 0; r < 4; ++r) {
                int vv = ma * 16 + g * 4 + r;
                out[((long)b * 32 + vv) * 128 + o] = fmaxf(acc2[ma][nb][r] + bia, 0.f);
            }
        }
}

// ---------------- fc2 ----------------
__global__ void fc2_kernel(const float* __restrict__ x, const float* __restrict__ w,
                           const float* __restrict__ bv, float* __restrict__ out)
{
    int tid = threadIdx.x;   // 128 threads
    int b = tid >> 1, o = tid & 1;
    float acc = bv[o];
    for (int f = 0; f < 512; ++f) acc = fmaf(x[b * 512 + f], w[o * 512 + f], acc);
    out[tid] = acc;
}

// ---------------- launch ----------------
extern "C" void kernel_launch(void* const* d_in, const int* in_sizes, int n_in,
                              void* d_out, int out_size, void* d_ws, size_t ws_size,
                              hipStream_t stream)
{
    const float* inp    = (const float*)d_in[0];
    const float* L0     = (const float*)d_in[2];
    const float* L1m    = (const float*)d_in[3];
    const int*   lmax0  = (const int*)d_in[4];
    const int*   lmax1  = (const int*)d_in[5];
    const int*   perm   = (const int*)d_in[6];
    const float* conv1_w = (const float*)d_in[8];
    const float* conv1_b = (const float*)d_in[9];
    const float* bn1_g  = (const float*)d_in[10];
    const float* bn1_b  = (const float*)d_in[11];
    const float* conv2_w = (const float*)d_in[12];
    const float* conv2_b = (const float*)d_in[13];
    const float* bn2_g  = (const float*)d_in[14];
    const float* bn2_b  = (const float*)d_in[15];
    const float* lin1_w = (const float*)d_in[16];
    const float* lin1_b = (const float*)d_in[17];
    const float* cl1_w  = (const float*)d_in[18];
    const float* cl1_b  = (const float*)d_in[19];
    const float* gbn1_g = (const float*)d_in[20];
    const float* gbn1_b = (const float*)d_in[21];
    const float* cl2_w  = (const float*)d_in[22];
    const float* cl2_b  = (const float*)d_in[23];
    const float* gbn2_g = (const float*)d_in[24];
    const float* gbn2_b = (const float*)d_in[25];
    const float* fc1_w  = (const float*)d_in[26];
    const float* fc1_b  = (const float*)d_in[27];
    const float* fc2_w  = (const float*)d_in[28];
    const float* fc2_b  = (const float*)d_in[29];
    float* ws  = (float*)d_ws;
    char*  wsb = (char*)d_ws;
    float* out = (float*)d_out;

    unsigned short* w1rb = (unsigned short*)(wsb + W1RB_B);
    unsigned short* w2rb = (unsigned short*)(wsb + W2RB_B);
    unsigned short* w2b  = (unsigned short*)(wsb + W2B_B);
    unsigned short* p1b  = (unsigned short*)(wsb + P1B_B);
    float*          y2   = (float*)(wsb + Y2_B);
    unsigned short* qb   = (unsigned short*)(wsb + QB_B);
    float*          co   = (float*)(wsb + CO_B);
    float*          xk   = (float*)(wsb + XK_B);
    float*          ch1  = (float*)(wsb + CH1_B);
    float*          x2k0 = (float*)(wsb + X2K_B);
    float*          ch2  = (float*)(wsb + CH2_B);
    unsigned short* fci  = (unsigned short*)(wsb + FCI_B);
    float*          fo1  = (float*)(wsb + FO1_B);
    float*          lr0  = (float*)(wsb + LR0_B);
    float*          lr1  = (float*)(wsb + LR1_B);

    // 0. prep (also zeroes conv2 stat accumulators)
    prep_kernel<<<9044, 256, 0, stream>>>(L0, L1m, lmax0, lmax1, cl1_w, cl2_w, conv2_w, ws);

    // 1. conv1 stats + recompute/bn/pool -> p1b bf16
    conv1_stats_kernel<<<2048, 256, 0, stream>>>(inp, conv1_w, conv1_b, ws);
    conv1_bnpool_kernel<<<2048, 256, 0, stream>>>(inp, conv1_w, conv1_b, bn1_g, bn1_b, ws, p1b);

    // 2. conv2 MFMA -> y2 [c][b][l][o2]; bn+pool (stats inline) -> qb bf16
    conv2_mfma_kernel<<<dim3(55, 64), 256, 0, stream>>>(p1b, w2b, conv2_b, y2, ws + S2S, ws + S2Q);
    bn2_pool_kernel<<<27648, 256, 0, stream>>>(y2, ws, bn2_g, bn2_b, qb);

    // 3. lin1 MFMA -> co fp32
    gemm_a16w32_kernel<<<dim3(8, 64), 256, 0, stream>>>(qb, lin1_w, lin1_b, co,
        LIN1K, 512, (long)64 * LIN1K, (long)512 * LIN1K, 512, (long)64 * 512);

    // 4. cheby layer 1: recursion (perm-gather + x0 write-through folded into step 1)
    const long XKS = (long)Cn * Bn * FIN1;   // 2097152
    cheby_rec64_kernel<<<256, 256, 0, stream>>>(lr0, co, perm, nullptr, xk + XKS, xk, 0);
    cheby_rec64_kernel<<<256, 256, 0, stream>>>(lr0, xk + XKS,     nullptr, xk,           xk + 2 * XKS, nullptr, 1);
    cheby_rec64_kernel<<<256, 256, 0, stream>>>(lr0, xk + 2 * XKS, nullptr, xk + XKS,     xk + 3 * XKS, nullptr, 1);
    cheby_rec64_kernel<<<256, 256, 0, stream>>>(lr0, xk + 3 * XKS, nullptr, xk + 2 * XKS, xk + 4 * XKS, nullptr, 1);
    cheby1_mfma_kernel<<<256, 256, 0, stream>>>(xk, w1rb, cl1_b, ch1);

    // 5. gbn1 + gpool1 -> x2k0 [v'][b][f]
    gbn_gpool_kernel<64, 1><<<32, 256, 0, stream>>>(ch1, gbn1_g, gbn1_b, 64.0f, 64, x2k0);

    // 6. fused layer 2 (recursion + cheby GEMM) -> ch2 [b][v][o]
    layer2_kernel<<<64, 256, 0, stream>>>(x2k0, lr1, w2rb, cl2_b, ch2);

    // 7. gbn2 + gpool2 -> fci bf16 [b][2048]
    gbn2_bf16_kernel<<<16, 256, 0, stream>>>(ch2, gbn2_g, gbn2_b, fci);

    // 8. fc1 MFMA + fc2
    gemm_a16w32_kernel<<<dim3(8, 1), 256, 0, stream>>>(fci, fc1_w, fc1_b, fo1,
        2048, 512, 0, 0, 0, 0);
    fc2_kernel<<<1, 128, 0, stream>>>(fo1, fc2_w, fc2_b, out);
}

// Round 4
// 397.077 us; speedup vs baseline: 2.3539x; 1.1548x over previous
//
#include <hip/hip_runtime.h>
#include <hip/hip_bf16.h>

typedef __attribute__((ext_vector_type(8))) short short8;
typedef __attribute__((ext_vector_type(4))) float f32x4;

// ---------------- constants ----------------
namespace {
constexpr int Bn  = 64;
constexpr int Cn  = 64;
constexpr int C1O = 32, C2O = 64;
constexpr int L1O = 249, L1P = 124;
constexpr int L2O = 55,  L2P = 27;
constexpr int FIN1 = 512;
constexpr int LIN1K = C2O * L2P;      // 1728

// stats floats
constexpr long S1S = 0;          // 2048 conv1 sum
constexpr long S1Q = 2048;       // 2048 conv1 sumsq
constexpr long S2S = 4096;       // 4096 conv2 sum
constexpr long S2Q = 8192;       // 4096 conv2 sumsq   (all zeroed by prep)

// byte offsets
constexpr long LR0_B  = 65536;       // 4096 f
constexpr long LR1_B  = 81920;       // 1024 f
constexpr long W1RB_B = 86016;       // 163840 bf16
constexpr long W2RB_B = 413696;      // 40960 bf16
constexpr long W2B_B  = 495616;      // 2097152 bf16 -> 4689920
constexpr long P1B_B  = 4689920;     // 16252928 bf16 -> 37195776
constexpr long Y2_B   = 37195776;    // 14417920 bf16 -> 66031616
constexpr long QB_B   = 94867456;    // 7077888 bf16
constexpr long CO_B   = 109023232;   // 2097152 f
constexpr long XK_B   = 4689920;     // alias p1b/y2 (dead): 5*2097152 f -> 46632960
constexpr long CH1_B  = 117411840;   // 262144 f
constexpr long X2K_B  = 118460416;   // 131072 f
constexpr long CH2_B  = 118984704;   // 262144 f
constexpr long FCI_B  = 120033280;   // 131072 bf16
constexpr long FO1_B  = 120295424;   // 32768 f
}

__device__ __forceinline__ unsigned short f2bf(float f) {
    union { float f; unsigned u; } v; v.f = f;
    unsigned r = v.u + 0x7FFFu + ((v.u >> 16) & 1u);
    return (unsigned short)(r >> 16);
}
__device__ __forceinline__ float bf2f(unsigned short s) {
    union { unsigned u; float f; } v; v.u = ((unsigned)s) << 16;
    return v.f;
}
__device__ __forceinline__ short8 cvt8(float4 a, float4 b) {
    float f[8] = {a.x, a.y, a.z, a.w, b.x, b.y, b.z, b.w};
    union { unsigned short s[8]; short8 v; } r;
#pragma unroll
    for (int i = 0; i < 8; ++i) r.s[i] = f2bf(f[i]);
    return r.v;
}

// ---------------- prep: zero stats + Lr + cheby bf16 repacks + conv2_w bf16 ----------------
__global__ void prep_kernel(const float* __restrict__ L0, const float* __restrict__ L1m,
                            const int* __restrict__ lmax0, const int* __restrict__ lmax1,
                            const float* __restrict__ cl1w, const float* __restrict__ cl2w,
                            const float* __restrict__ conv2w, float* __restrict__ ws)
{
    long idx = (long)blockIdx.x * 256 + threadIdx.x;
    float inv0 = 2.0f / (float)lmax0[0];
    float inv1 = 2.0f / (float)lmax1[0];
    char* wsb = (char*)ws;
    float* LR0p = (float*)(wsb + LR0_B);
    float* LR1p = (float*)(wsb + LR1_B);
    unsigned short* W1Rp = (unsigned short*)(wsb + W1RB_B);
    unsigned short* W2Rp = (unsigned short*)(wsb + W2RB_B);
    unsigned short* w2b  = (unsigned short*)(wsb + W2B_B);
    if (idx < 12288) {
        ws[idx] = 0.f;
    } else if (idx < 12288 + 4096) {
        long t = idx - 12288; int i = t / 64, j = t % 64;
        LR0p[t] = L0[t] * inv0 - (i == j ? 1.0f : 0.0f);
    } else if (idx < 12288 + 4096 + 1024) {
        long t = idx - 12288 - 4096; int i = t / 32, j = t % 32;
        LR1p[t] = L1m[t] * inv1 - (i == j ? 1.0f : 0.0f);
    } else if (idx < 12288 + 4096 + 1024 + 163840) {
        long t = idx - 12288 - 4096 - 1024;
        int k = t / 32768; int r = t % 32768; int o = r / 512, f = r % 512;
        W1Rp[t] = f2bf(cl1w[o * 2560 + f * 5 + k]);
    } else if (idx < 12288 + 4096 + 1024 + 163840 + 40960) {
        long t = idx - 12288 - 4096 - 1024 - 163840;
        int k = t / 8192; int r = t % 8192; int o = r / 64, f = r % 64;
        W2Rp[t] = f2bf(cl2w[o * 320 + f * 5 + k]);
    } else if (idx < 12288 + 4096 + 1024 + 163840 + 40960 + 2097152) {
        long t = idx - 12288 - 4096 - 1024 - 163840 - 40960;
        w2b[t] = f2bf(conv2w[t]);
    }
}

// ---------------- conv1 pass1: conv+relu+stats; block = (c, 8-batch group) ----------------
__global__ __launch_bounds__(256) void conv1_p1_kernel(const float* __restrict__ inp,
    const float* __restrict__ w1, const float* __restrict__ b1, float* __restrict__ ws)
{
    int c = blockIdx.x >> 3, bg = blockIdx.x & 7;
    __shared__ float xs[8][512];
    __shared__ float rs[8][32], rq[8][32];
    int tid = threadIdx.x;
#pragma unroll
    for (int it = 0; it < 4; ++it) {
        int f4 = it * 256 + tid;
        int bl = f4 >> 7, off = (f4 & 127) * 4;
        *(float4*)&xs[bl][off] = *(const float4*)&inp[((long)(bg * 8 + bl) * 64 + c) * 512 + off];
    }
    int o = tid & 31, bq = tid >> 5;
    int co = c * 32 + o;
    float w[16];
#pragma unroll
    for (int t = 0; t < 16; ++t) w[t] = w1[co * 16 + t];
    float bias = b1[co];
    __syncthreads();
    float s = 0.f, q = 0.f;
    for (int jg = 0; jg < 31; ++jg) {
        float x[32];
#pragma unroll
        for (int h = 0; h < 8; ++h) *(float4*)&x[h * 4] = *(const float4*)&xs[bq][jg * 16 + h * 4];
#pragma unroll
        for (int j = 0; j < 8; ++j) {
            float a = bias;
#pragma unroll
            for (int t = 0; t < 16; ++t) a = fmaf(x[2 * j + t], w[t], a);
            a = fmaxf(a, 0.f);
            s += a; q += a * a;
        }
    }
    {   // l = 248
        float x[16];
#pragma unroll
        for (int h = 0; h < 4; ++h) *(float4*)&x[h * 4] = *(const float4*)&xs[bq][496 + h * 4];
        float a = bias;
#pragma unroll
        for (int t = 0; t < 16; ++t) a = fmaf(x[t], w[t], a);
        a = fmaxf(a, 0.f);
        s += a; q += a * a;
    }
    rs[bq][o] = s; rq[bq][o] = q;
    __syncthreads();
    if (tid < 32) {
        float ss = 0.f, qq = 0.f;
#pragma unroll
        for (int i = 0; i < 8; ++i) { ss += rs[i][tid]; qq += rq[i][tid]; }
        atomicAdd(&ws[S1S + c * 32 + tid], ss);
        atomicAdd(&ws[S1Q + c * 32 + tid], qq);
    }
}

// ---------------- conv1 pass2: conv+bn+pool -> p1b bf16 [c][b][o][124] ----------------
__global__ __launch_bounds__(256) void conv1_p2_kernel(const float* __restrict__ inp,
    const float* __restrict__ w1, const float* __restrict__ b1,
    const float* __restrict__ g, const float* __restrict__ be,
    const float* __restrict__ ws, unsigned short* __restrict__ p1)
{
    int c = blockIdx.x >> 3, bg = blockIdx.x & 7;
    __shared__ float xs[8][512];
    int tid = threadIdx.x;
#pragma unroll
    for (int it = 0; it < 4; ++it) {
        int f4 = it * 256 + tid;
        int bl = f4 >> 7, off = (f4 & 127) * 4;
        *(float4*)&xs[bl][off] = *(const float4*)&inp[((long)(bg * 8 + bl) * 64 + c) * 512 + off];
    }
    int o = tid & 31, bq = tid >> 5;
    int co = c * 32 + o;
    float w[16];
#pragma unroll
    for (int t = 0; t < 16; ++t) w[t] = w1[co * 16 + t];
    float bias = b1[co];
    float N = (float)(Bn * L1O);
    float m = ws[S1S + co] / N;
    float inv = rsqrtf(ws[S1Q + co] / N - m * m + 1e-5f);
    float sc = inv * g[co], sh = be[co] - m * sc;
    __syncthreads();
    unsigned short* op = p1 + ((long)(c * 64 + bg * 8 + bq) * 32 + o) * 124;
    for (int jg = 0; jg < 31; ++jg) {
        float x[32];
#pragma unroll
        for (int h = 0; h < 8; ++h) *(float4*)&x[h * 4] = *(const float4*)&xs[bq][jg * 16 + h * 4];
        union { unsigned short r[4]; uint2 u; } pk;
#pragma unroll
        for (int p = 0; p < 4; ++p) {
            float a0 = bias, a1 = bias;
#pragma unroll
            for (int t = 0; t < 16; ++t) {
                a0 = fmaf(x[4 * p + t], w[t], a0);
                a1 = fmaf(x[4 * p + 2 + t], w[t], a1);
            }
            float v0 = fmaxf(a0, 0.f) * sc + sh;
            float v1 = fmaxf(a1, 0.f) * sc + sh;
            pk.r[p] = f2bf(fmaxf(v0, v1));
        }
        *(uint2*)&op[jg * 4] = pk.u;
    }
}

// ---------------- conv2 MFMA GEMM, M-tile 128 + relu + stats; y2 bf16 [c][b][l][o2] ----------------
__global__ __launch_bounds__(256) void conv2_mfma_kernel(const unsigned short* __restrict__ p1b,
    const unsigned short* __restrict__ w2b, const float* __restrict__ b2,
    unsigned short* __restrict__ y2b, float* __restrict__ s2s, float* __restrict__ s2q)
{
    int c = blockIdx.y;
    int m0 = blockIdx.x * 128;
    __shared__ unsigned short Bl[64 * 512];
    __shared__ float red[2][4][64];
    int tid = threadIdx.x;
    int w = tid >> 6, lane = tid & 63;
    int lx = lane & 15, g = lane >> 4;

    const unsigned short* wsrc = w2b + (long)c * 32768;
#pragma unroll
    for (int it = 0; it < 16; ++it) {
        int j = it * 256 + tid;
        int n = j >> 6, kb = j & 63;
        uint4 val = *(const uint4*)(wsrc + n * 512 + kb * 8);
        int dst = (n * 1024 + kb * 16) ^ ((n & 7) << 4);
        *(uint4*)((char*)Bl + dst) = val;
    }
    __syncthreads();

    const unsigned short* abase[2];
#pragma unroll
    for (int ma = 0; ma < 2; ++ma) {
        int m = m0 + w * 32 + ma * 16 + lx;
        m = min(m, 3519);
        int b = m / 55, lp = m % 55;
        abase[ma] = p1b + ((long)(c * 64 + b) * 32) * 124 + 2 * lp + (g & 1) * 8;
    }
    int cio = g >> 1;

    f32x4 acc[2][4] = {};
    for (int kstep = 0; kstep < 16; ++kstep) {
        short8 af[2];
#pragma unroll
        for (int ma = 0; ma < 2; ++ma) {
            const unsigned short* ap = abase[ma] + (kstep * 2 + cio) * 124;
            union { unsigned u[4]; short8 v; } t;
            t.u[0] = *(const unsigned*)(ap + 0);
            t.u[1] = *(const unsigned*)(ap + 2);
            t.u[2] = *(const unsigned*)(ap + 4);
            t.u[3] = *(const unsigned*)(ap + 6);
            af[ma] = t.v;
        }
#pragma unroll
        for (int fi = 0; fi < 4; ++fi) {
            int n = fi * 16 + lx;
            int off = (n * 1024 + kstep * 64 + g * 16) ^ ((n & 7) << 4);
            short8 bfrag = *(const short8*)((char*)Bl + off);
#pragma unroll
            for (int ma = 0; ma < 2; ++ma)
                acc[ma][fi] = __builtin_amdgcn_mfma_f32_16x16x32_bf16(af[ma], bfrag, acc[ma][fi], 0, 0, 0);
        }
    }

    float cs[4] = {}, cq[4] = {};
#pragma unroll
    for (int fi = 0; fi < 4; ++fi) {
        int o2 = fi * 16 + lx;
        float bia = b2[c * 64 + o2];
#pragma unroll
        for (int ma = 0; ma < 2; ++ma) {
#pragma unroll
            for (int r = 0; r < 4; ++r) {
                int mm = m0 + w * 32 + ma * 16 + g * 4 + r;
                if (mm < 3520) {
                    int bb = mm / 55, ll = mm % 55;
                    float y = fmaxf(acc[ma][fi][r] + bia, 0.f);
                    y2b[((long)(c * 64 + bb) * 55 + ll) * 64 + o2] = f2bf(y);
                    cs[fi] += y; cq[fi] += y * y;
                }
            }
        }
    }
#pragma unroll
    for (int fi = 0; fi < 4; ++fi) {
        cs[fi] += __shfl_xor(cs[fi], 16); cs[fi] += __shfl_xor(cs[fi], 32);
        cq[fi] += __shfl_xor(cq[fi], 16); cq[fi] += __shfl_xor(cq[fi], 32);
    }
    __syncthreads();
    if (g == 0) {
#pragma unroll
        for (int fi = 0; fi < 4; ++fi) { red[0][w][fi * 16 + lx] = cs[fi]; red[1][w][fi * 16 + lx] = cq[fi]; }
    }
    __syncthreads();
    if (tid < 64) {
        float ss = red[0][0][tid] + red[0][1][tid] + red[0][2][tid] + red[0][3][tid];
        float qq = red[1][0][tid] + red[1][1][tid] + red[1][2][tid] + red[1][3][tid];
        atomicAdd(&s2s[c * 64 + tid], ss);
        atomicAdd(&s2q[c * 64 + tid], qq);
    }
}

// ---------------- conv2 bn + pool -> qb bf16 [c][b][o2*27+j]; linear index = qb index ----------------
__global__ void bn2_pool_kernel(const unsigned short* __restrict__ y2b, const float* __restrict__ ws,
    const float* __restrict__ g, const float* __restrict__ be, unsigned short* __restrict__ q)
{
    long idx = (long)blockIdx.x * 256 + threadIdx.x;
    if (idx >= (long)Cn * Bn * C2O * L2P) return;
    int j = idx % 27; long r = idx / 27;
    int o2 = r & 63; long r2 = r >> 6;
    int b = r2 & 63; int c = r2 >> 6;
    int co = c * 64 + o2;
    float N = (float)(Bn * L2O);
    float m = ws[S2S + co] / N;
    float inv = rsqrtf(ws[S2Q + co] / N - m * m + 1e-5f);
    float sc = inv * g[co], sh = be[co] - m * sc;
    const unsigned short* yb = y2b + ((long)(c * 64 + b) * 55 + 2 * j) * 64 + o2;
    float v = fmaxf(sc * bf2f(yb[0]) + sh, sc * bf2f(yb[64]) + sh);
    q[idx] = f2bf(v);
}

// ---------------- generic MFMA GEMM: C[64,Ntot] = relu(A_bf16[64,K] @ W_fp32[Ntot,K]^T + bias) ----------------
__global__ __launch_bounds__(256) void gemm_a16w32_kernel(const unsigned short* __restrict__ A,
    const float* __restrict__ W, const float* __restrict__ bias, float* __restrict__ C,
    int K, int Ntot, long sA, long sW, long sB, long sC)
{
    int c = blockIdx.y;
    A += (long)c * sA; W += (long)c * sW; bias += (long)c * sB; C += (long)c * sC;
    int n0 = blockIdx.x * 64;
    int tid = threadIdx.x, wv = tid >> 6, lane = tid & 63;
    int lx = lane & 15, g = lane >> 4;
    int wm = wv & 1, wn = wv >> 1;

    const unsigned short* a0 = A + (long)(wm * 32 + lx) * K + g * 8;
    const float* w0 = W + (long)(n0 + wn * 32 + lx) * K + g * 8;
    int ksteps = K >> 5;

    f32x4 acc[2][2] = {};
    for (int kstep = 0; kstep < ksteps; ++kstep) {
        short8 af[2];
        af[0] = *(const short8*)(a0 + kstep * 32);
        af[1] = *(const short8*)(a0 + (long)16 * K + kstep * 32);
        short8 bf[2];
#pragma unroll
        for (int nb = 0; nb < 2; ++nb) {
            const float* wp = w0 + (long)nb * 16 * K + kstep * 32;
            float4 x = *(const float4*)(wp);
            float4 y = *(const float4*)(wp + 4);
            bf[nb] = cvt8(x, y);
        }
#pragma unroll
        for (int ma = 0; ma < 2; ++ma)
#pragma unroll
            for (int nb = 0; nb < 2; ++nb)
                acc[ma][nb] = __builtin_amdgcn_mfma_f32_16x16x32_bf16(af[ma], bf[nb], acc[ma][nb], 0, 0, 0);
    }
#pragma unroll
    for (int ma = 0; ma < 2; ++ma)
#pragma unroll
        for (int nb = 0; nb < 2; ++nb) {
            int o = n0 + wn * 32 + nb * 16 + lx;
            float bia = bias[o];
#pragma unroll
            for (int r = 0; r < 4; ++r) {
                int b = wm * 32 + ma * 16 + g * 4 + r;
                C[(long)b * Ntot + o] = fmaxf(acc[ma][nb][r] + bia, 0.f);
            }
        }
}

// ---------------- fused chebyshev recursion V=64: x0..x4 in one kernel (per-column independent) ----------------
__global__ __launch_bounds__(256) void rec_fused_kernel(const float* __restrict__ Lr,
    const float* __restrict__ co, const int* __restrict__ perm, float* __restrict__ xk)
{
    __shared__ float Lt[64 * 64];     // Lt[u][v] = Lr[v][u]
    __shared__ float xA[64][130];
    __shared__ float xB[64][130];
    int tid = threadIdx.x;
    for (int i = tid; i < 4096; i += 256) Lt[(i & 63) * 64 + (i >> 6)] = Lr[i];
    int cg = tid & 31, vg = tid >> 5;
    int col = blockIdx.x * 128 + cg * 4;
#pragma unroll
    for (int i = 0; i < 8; ++i) {
        int v = vg * 8 + i;
        float4 x = *(const float4*)&co[(long)perm[v] * 32768 + col];
        *(float4*)&xA[v][cg * 4] = x;
        *(float4*)&xk[(long)v * 32768 + col] = x;
    }
    __syncthreads();
#pragma unroll
    for (int k = 1; k <= 4; ++k) {
        float (*prev)[130] = (k & 1) ? xA : xB;
        float (*dst)[130]  = (k & 1) ? xB : xA;
        float acc[8][4] = {};
        for (int u = 0; u < 64; ++u) {
            float4 xv = *(const float4*)&prev[u][cg * 4];
            float4 l0 = *(const float4*)&Lt[u * 64 + vg * 8];
            float4 l1 = *(const float4*)&Lt[u * 64 + vg * 8 + 4];
            float lv[8] = {l0.x, l0.y, l0.z, l0.w, l1.x, l1.y, l1.z, l1.w};
#pragma unroll
            for (int i = 0; i < 8; ++i) {
                acc[i][0] = fmaf(lv[i], xv.x, acc[i][0]);
                acc[i][1] = fmaf(lv[i], xv.y, acc[i][1]);
                acc[i][2] = fmaf(lv[i], xv.z, acc[i][2]);
                acc[i][3] = fmaf(lv[i], xv.w, acc[i][3]);
            }
        }
#pragma unroll
        for (int i = 0; i < 8; ++i) {
            int v = vg * 8 + i;
            float4 r;
            if (k == 1) {
                r.x = acc[i][0]; r.y = acc[i][1]; r.z = acc[i][2]; r.w = acc[i][3];
            } else {
                float4 p = *(const float4*)&dst[v][cg * 4];   // holds x_{k-2}
                r.x = 2.f * acc[i][0] - p.x; r.y = 2.f * acc[i][1] - p.y;
                r.z = 2.f * acc[i][2] - p.z; r.w = 2.f * acc[i][3] - p.w;
            }
            *(float4*)&dst[v][cg * 4] = r;
            *(float4*)&xk[(long)k * 2097152 + (long)v * 32768 + col] = r;
        }
        __syncthreads();
    }
}

// ---------------- cheby layer-1 output GEMM, M-tile 16, bf16 weights ----------------
__global__ __launch_bounds__(256) void cheby1_mfma_kernel(const float* __restrict__ xk,
    const unsigned short* __restrict__ w1rb, const float* __restrict__ bias, float* __restrict__ out)
{
    int m0 = blockIdx.x * 16;
    __shared__ unsigned short Bl[64 * 512];
    int tid = threadIdx.x, wv = tid >> 6, lane = tid & 63;
    int lx = lane & 15, g = lane >> 4;
    int m = m0 + lx;
    int v = m & 63, b = m >> 6;

    f32x4 acc = {};
    for (int kc = 0; kc < 5; ++kc) {
        __syncthreads();
#pragma unroll
        for (int it = 0; it < 16; ++it) {
            int j = it * 256 + tid;
            int n = j >> 6, kb = j & 63;
            uint4 val = *(const uint4*)(w1rb + (long)kc * 32768 + n * 512 + kb * 8);
            int dst = (n * 1024 + kb * 16) ^ ((n & 7) << 4);
            *(uint4*)((char*)Bl + dst) = val;
        }
        __syncthreads();
        const float* ab = xk + ((long)(kc * 64 + v) * 64 + b) * 512 + g * 8;
        for (int kl = 0; kl < 16; ++kl) {
            float4 x = *(const float4*)(ab + kl * 32);
            float4 y = *(const float4*)(ab + kl * 32 + 4);
            short8 af = cvt8(x, y);
            int n = wv * 16 + lx;
            int off = (n * 1024 + kl * 64 + g * 16) ^ ((n & 7) << 4);
            short8 bfrag = *(const short8*)((char*)Bl + off);
            acc = __builtin_amdgcn_mfma_f32_16x16x32_bf16(af, bfrag, acc, 0, 0, 0);
        }
    }
    int o = wv * 16 + lx;
    float bia = bias[o];
#pragma unroll
    for (int r = 0; r < 4; ++r) {
        int mm = m0 + g * 4 + r;
        int vv = mm & 63, bb = mm >> 6;
        out[((long)(bb * 64 + vv)) * 64 + o] = fmaxf(acc[r] + bia, 0.f);
    }
}

// ---------------- graph BN + graph max-pool (fp32 out, cheby layout) ----------------
template<int Fdim, int XOUT>
__global__ __launch_bounds__(256) void gbn_gpool_kernel(const float* __restrict__ y,
    const float* __restrict__ g, const float* __restrict__ be, float eps, int V, float* __restrict__ out)
{
    int j = blockIdx.x; int v0 = 2 * j;
    int tid = threadIdx.x;
    float s0 = 0.f, q0 = 0.f, s1 = 0.f, q1 = 0.f;
    int Ntot = Bn * Fdim;
    for (int idx = tid; idx < Ntot; idx += 256) {
        int b = idx / Fdim, f = idx % Fdim;
        float a = y[((long)b * V + v0) * Fdim + f];
        float c = y[((long)b * V + v0 + 1) * Fdim + f];
        s0 += a; q0 += a * a; s1 += c; q1 += c * c;
    }
    __shared__ float red[4][256];
    red[0][tid] = s0; red[1][tid] = q0; red[2][tid] = s1; red[3][tid] = q1;
    __syncthreads();
    for (int st = 128; st > 0; st >>= 1) {
        if (tid < st) {
#pragma unroll
            for (int r = 0; r < 4; ++r) red[r][tid] += red[r][tid + st];
        }
        __syncthreads();
    }
    float N = (float)Ntot;
    float m0 = red[0][0] / N, i0 = rsqrtf(red[1][0] / N - m0 * m0 + eps);
    float m1 = red[2][0] / N, i1 = rsqrtf(red[3][0] / N - m1 * m1 + eps);
    float sc0 = i0 * g[v0], sh0 = be[v0] - m0 * sc0;
    float sc1 = i1 * g[v0 + 1], sh1 = be[v0 + 1] - m1 * sc1;
    for (int idx = tid; idx < Ntot; idx += 256) {
        int b = idx / Fdim, f = idx % Fdim;
        float a = y[((long)b * V + v0) * Fdim + f];
        float c = y[((long)b * V + v0 + 1) * Fdim + f];
        float r = fmaxf(sc0 * a + sh0, sc1 * c + sh1);
        long oidx = XOUT ? ((long)j * Bn + b) * Fdim + f : ((long)b * (V / 2) + j) * Fdim + f;
        out[oidx] = r;
    }
}

// ---------------- gbn2 + gpool2, bf16 out [b][j*128+f] ----------------
__global__ __launch_bounds__(256) void gbn2_bf16_kernel(const float* __restrict__ y,
    const float* __restrict__ g, const float* __restrict__ be, unsigned short* __restrict__ out)
{
    constexpr int Fdim = 128; constexpr int V = 32;
    int j = blockIdx.x; int v0 = 2 * j;
    int tid = threadIdx.x;
    float s0 = 0.f, q0 = 0.f, s1 = 0.f, q1 = 0.f;
    int Ntot = Bn * Fdim;
    for (int idx = tid; idx < Ntot; idx += 256) {
        int b = idx / Fdim, f = idx % Fdim;
        float a = y[((long)b * V + v0) * Fdim + f];
        float c = y[((long)b * V + v0 + 1) * Fdim + f];
        s0 += a; q0 += a * a; s1 += c; q1 += c * c;
    }
    __shared__ float red[4][256];
    red[0][tid] = s0; red[1][tid] = q0; red[2][tid] = s1; red[3][tid] = q1;
    __syncthreads();
    for (int st = 128; st > 0; st >>= 1) {
        if (tid < st) {
#pragma unroll
            for (int r = 0; r < 4; ++r) red[r][tid] += red[r][tid + st];
        }
        __syncthreads();
    }
    float N = (float)Ntot;
    float m0 = red[0][0] / N, i0 = rsqrtf(red[1][0] / N - m0 * m0 + 128.0f);
    float m1 = red[2][0] / N, i1 = rsqrtf(red[3][0] / N - m1 * m1 + 128.0f);
    float sc0 = i0 * g[v0], sh0 = be[v0] - m0 * sc0;
    float sc1 = i1 * g[v0 + 1], sh1 = be[v0 + 1] - m1 * sc1;
    for (int idx = tid; idx < Ntot; idx += 256) {
        int b = idx / Fdim, f = idx % Fdim;
        float a = y[((long)b * V + v0) * Fdim + f];
        float c = y[((long)b * V + v0 + 1) * Fdim + f];
        float r = fmaxf(sc0 * a + sh0, sc1 * c + sh1);
        out[((long)b * 16 + j) * Fdim + f] = f2bf(r);
    }
}

// ---------------- fused layer 2: cheby recursion (LDS) + MFMA GEMM, one block per b ----------------
__global__ __launch_bounds__(256) void layer2_kernel(const float* __restrict__ x2k0,
    const float* __restrict__ Lr1, const unsigned short* __restrict__ w2rb,
    const float* __restrict__ bias, float* __restrict__ out)
{
    int b = blockIdx.x;
    __shared__ float xs[5][32][72];
    __shared__ unsigned short wsl[128 * 320];
    int tid = threadIdx.x;
#pragma unroll
    for (int it = 0; it < 20; ++it) {
        int j = it * 256 + tid;
        int o = j / 40, kb = j % 40;
        uint4 val = *(const uint4*)(w2rb + ((long)(kb >> 3) * 128 + o) * 64 + (kb & 7) * 8);
        int dst = (o * 640 + kb * 16) ^ ((o & 7) << 4);
        *(uint4*)((char*)wsl + dst) = val;
    }
    int v = tid & 31, fg = tid >> 5;
    float lrow[32];
#pragma unroll
    for (int u = 0; u < 32; ++u) lrow[u] = Lr1[v * 32 + u];
    {
        const float* sp = x2k0 + ((long)v * 64 + b) * 64 + fg * 8;
        float4 a = *(const float4*)sp;
        float4 c = *(const float4*)(sp + 4);
        *(float4*)&xs[0][v][fg * 8] = a;
        *(float4*)&xs[0][v][fg * 8 + 4] = c;
    }
    __syncthreads();
    for (int k = 1; k < 5; ++k) {
        float acc[8] = {};
#pragma unroll
        for (int u = 0; u < 32; ++u) {
            float4 xa = *(const float4*)&xs[k - 1][u][fg * 8];
            float4 xb = *(const float4*)&xs[k - 1][u][fg * 8 + 4];
            float l = lrow[u];
            acc[0] = fmaf(l, xa.x, acc[0]); acc[1] = fmaf(l, xa.y, acc[1]);
            acc[2] = fmaf(l, xa.z, acc[2]); acc[3] = fmaf(l, xa.w, acc[3]);
            acc[4] = fmaf(l, xb.x, acc[4]); acc[5] = fmaf(l, xb.y, acc[5]);
            acc[6] = fmaf(l, xb.z, acc[6]); acc[7] = fmaf(l, xb.w, acc[7]);
        }
        float4 ra, rb;
        if (k >= 2) {
            float4 pa = *(const float4*)&xs[k - 2][v][fg * 8];
            float4 pb = *(const float4*)&xs[k - 2][v][fg * 8 + 4];
            ra.x = 2.f * acc[0] - pa.x; ra.y = 2.f * acc[1] - pa.y;
            ra.z = 2.f * acc[2] - pa.z; ra.w = 2.f * acc[3] - pa.w;
            rb.x = 2.f * acc[4] - pb.x; rb.y = 2.f * acc[5] - pb.y;
            rb.z = 2.f * acc[6] - pb.z; rb.w = 2.f * acc[7] - pb.w;
        } else {
            ra.x = acc[0]; ra.y = acc[1]; ra.z = acc[2]; ra.w = acc[3];
            rb.x = acc[4]; rb.y = acc[5]; rb.z = acc[6]; rb.w = acc[7];
        }
        *(float4*)&xs[k][v][fg * 8] = ra;
        *(float4*)&xs[k][v][fg * 8 + 4] = rb;
        __syncthreads();
    }
    int wv = tid >> 6, lane = tid & 63;
    int lx = lane & 15, g = lane >> 4;
    f32x4 acc2[2][2] = {};
    for (int kstep = 0; kstep < 10; ++kstep) {
        int k = kstep * 32 + g * 8;
        int kc = k >> 6, f = k & 63;
        short8 af[2];
#pragma unroll
        for (int ma = 0; ma < 2; ++ma) {
            int vv = ma * 16 + lx;
            float4 xa = *(const float4*)&xs[kc][vv][f];
            float4 xb = *(const float4*)&xs[kc][vv][f + 4];
            af[ma] = cvt8(xa, xb);
        }
#pragma unroll
        for (int nb = 0; nb < 2; ++nb) {
            int o = wv * 32 + nb * 16 + lx;
            int kb = kstep * 4 + g;
            int off = (o * 640 + kb * 16) ^ ((o & 7) << 4);
            short8 bf = *(const short8*)((char*)wsl + off);
#pragma unroll
            for (int ma = 0; ma < 2; ++ma)
                acc2[ma][nb] = __builtin_amdgcn_mfma_f32_16x16x32_bf16(af[ma], bf, acc2[ma][nb], 0, 0, 0);
        }
    }
#pragma unroll
    for (int ma = 0; ma < 2; ++ma)
#pragma unroll
        for (int nb = 0; nb < 2; ++nb) {
            int o = wv * 32 + nb * 16 + lx;
            float bia = bias[o];
#pragma unroll
            for (int r = 0; r < 4; ++r) {
                int vv = ma * 16 + g * 4 + r;
                out[((long)b * 32 + vv) * 128 + o] = fmaxf(acc2[ma][nb][r] + bia, 0.f);
            }
        }
}

// ---------------- fc2 ----------------
__global__ void fc2_kernel(const float* __restrict__ x, const float* __restrict__ w,
                           const float* __restrict__ bv, float* __restrict__ out)
{
    int tid = threadIdx.x;   // 128 threads
    int b = tid >> 1, o = tid & 1;
    float acc = bv[o];
    for (int f = 0; f < 512; ++f) acc = fmaf(x[b * 512 + f], w[o * 512 + f], acc);
    out[tid] = acc;
}

// ---------------- launch ----------------
extern "C" void kernel_launch(void* const* d_in, const int* in_sizes, int n_in,
                              void* d_out, int out_size, void* d_ws, size_t ws_size,
                              hipStream_t stream)
{
    const float* inp    = (const float*)d_in[0];
    const float* L0     = (const float*)d_in[2];
    const float* L1m    = (const float*)d_in[3];
    const int*   lmax0  = (const int*)d_in[4];
    const int*   lmax1  = (const int*)d_in[5];
    const int*   perm   = (const int*)d_in[6];
    const float* conv1_w = (const float*)d_in[8];
    const float* conv1_b = (const float*)d_in[9];
    const float* bn1_g  = (const float*)d_in[10];
    const float* bn1_b  = (const float*)d_in[11];
    const float* conv2_w = (const float*)d_in[12];
    const float* conv2_b = (const float*)d_in[13];
    const float* bn2_g  = (const float*)d_in[14];
    const float* bn2_b  = (const float*)d_in[15];
    const float* lin1_w = (const float*)d_in[16];
    const float* lin1_b = (const float*)d_in[17];
    const float* cl1_w  = (const float*)d_in[18];
    const float* cl1_b  = (const float*)d_in[19];
    const float* gbn1_g = (const float*)d_in[20];
    const float* gbn1_b = (const float*)d_in[21];
    const float* cl2_w  = (const float*)d_in[22];
    const float* cl2_b  = (const float*)d_in[23];
    const float* gbn2_g = (const float*)d_in[24];
    const float* gbn2_b = (const float*)d_in[25];
    const float* fc1_w  = (const float*)d_in[26];
    const float* fc1_b  = (const float*)d_in[27];
    const float* fc2_w  = (const float*)d_in[28];
    const float* fc2_b  = (const float*)d_in[29];
    float* ws  = (float*)d_ws;
    char*  wsb = (char*)d_ws;
    float* out = (float*)d_out;

    unsigned short* w1rb = (unsigned short*)(wsb + W1RB_B);
    unsigned short* w2rb = (unsigned short*)(wsb + W2RB_B);
    unsigned short* w2b  = (unsigned short*)(wsb + W2B_B);
    unsigned short* p1b  = (unsigned short*)(wsb + P1B_B);
    unsigned short* y2b  = (unsigned short*)(wsb + Y2_B);
    unsigned short* qb   = (unsigned short*)(wsb + QB_B);
    float*          co   = (float*)(wsb + CO_B);
    float*          xk   = (float*)(wsb + XK_B);
    float*          ch1  = (float*)(wsb + CH1_B);
    float*          x2k0 = (float*)(wsb + X2K_B);
    float*          ch2  = (float*)(wsb + CH2_B);
    unsigned short* fci  = (unsigned short*)(wsb + FCI_B);
    float*          fo1  = (float*)(wsb + FO1_B);
    float*          lr0  = (float*)(wsb + LR0_B);
    float*          lr1  = (float*)(wsb + LR1_B);

    // 0. prep (zeros all stat accumulators + Lr + repacks)
    prep_kernel<<<9060, 256, 0, stream>>>(L0, L1m, lmax0, lmax1, cl1_w, cl2_w, conv2_w, ws);

    // 1. conv1: stats pass + bn/pool pass -> p1b bf16
    conv1_p1_kernel<<<512, 256, 0, stream>>>(inp, conv1_w, conv1_b, ws);
    conv1_p2_kernel<<<512, 256, 0, stream>>>(inp, conv1_w, conv1_b, bn1_g, bn1_b, ws, p1b);

    // 2. conv2 MFMA (M-tile 128) -> y2 bf16; bn+pool (stats inline) -> qb bf16
    conv2_mfma_kernel<<<dim3(28, 64), 256, 0, stream>>>(p1b, w2b, conv2_b, y2b, ws + S2S, ws + S2Q);
    bn2_pool_kernel<<<27648, 256, 0, stream>>>(y2b, ws, bn2_g, bn2_b, qb);

    // 3. lin1 MFMA -> co fp32
    gemm_a16w32_kernel<<<dim3(8, 64), 256, 0, stream>>>(qb, lin1_w, lin1_b, co,
        LIN1K, 512, (long)64 * LIN1K, (long)512 * LIN1K, 512, (long)64 * 512);

    // 4. cheby layer 1: fused recursion (perm-gather + x0..x4) then MFMA output GEMM
    rec_fused_kernel<<<256, 256, 0, stream>>>(lr0, co, perm, xk);
    cheby1_mfma_kernel<<<256, 256, 0, stream>>>(xk, w1rb, cl1_b, ch1);

    // 5. gbn1 + gpool1 -> x2k0 [v'][b][f]
    gbn_gpool_kernel<64, 1><<<32, 256, 0, stream>>>(ch1, gbn1_g, gbn1_b, 64.0f, 64, x2k0);

    // 6. fused layer 2 (recursion + cheby GEMM) -> ch2 [b][v][o]
    layer2_kernel<<<64, 256, 0, stream>>>(x2k0, lr1, w2rb, cl2_b, ch2);

    // 7. gbn2 + gpool2 -> fci bf16 [b][2048]
    gbn2_bf16_kernel<<<16, 256, 0, stream>>>(ch2, gbn2_g, gbn2_b, fci);

    // 8. fc1 MFMA + fc2
    gemm_a16w32_kernel<<<dim3(8, 1), 256, 0, stream>>>(fci, fc1_w, fc1_b, fo1,
        2048, 512, 0, 0, 0, 0);
    fc2_kernel<<<1, 128, 0, stream>>>(fo1, fc2_w, fc2_b, out);
}

// Round 5
// 344.690 us; speedup vs baseline: 2.7116x; 1.1520x over previous
//
#include <hip/hip_runtime.h>
#include <hip/hip_bf16.h>

typedef __attribute__((ext_vector_type(8))) short short8;
typedef __attribute__((ext_vector_type(4))) float f32x4;

// ---------------- constants ----------------
namespace {
constexpr int Bn  = 64;
constexpr int Cn  = 64;
constexpr int C1O = 32, C2O = 64;
constexpr int L1O = 249, L1P = 124;
constexpr int L2O = 55,  L2P = 27;
constexpr int FIN1 = 512;
constexpr int LIN1K = C2O * L2P;      // 1728

// stats floats
constexpr long S1S = 0;          // 2048 conv1 sum
constexpr long S1Q = 2048;       // 2048 conv1 sumsq
constexpr long S2S = 4096;       // 4096 conv2 sum
constexpr long S2Q = 8192;       // 4096 conv2 sumsq   (all zeroed by prep)

// byte offsets
constexpr long LR0_B  = 65536;       // 4096 f
constexpr long LR1_B  = 81920;       // 1024 f
constexpr long W1RB_B = 86016;       // 163840 bf16
constexpr long W2RB_B = 413696;      // 40960 bf16
constexpr long W2B_B  = 495616;      // 2097152 bf16 -> 4689920
constexpr long P1B_B  = 4689920;     // 16252928 bf16 -> 37195776
constexpr long Y2_B   = 37195776;    // 14417920 bf16 -> 66031616
constexpr long QB_B   = 94867456;    // 7077888 bf16
constexpr long CO_B   = 109023232;   // 2097152 f
constexpr long XK_B   = 4689920;     // alias p1b/y2 (dead): 5*2097152 bf16 -> 25661440
constexpr long CH1_B  = 117411840;   // 262144 f
constexpr long X2K_B  = 118460416;   // 131072 f
constexpr long CH2_B  = 118984704;   // 262144 f
constexpr long FCI_B  = 120033280;   // 131072 bf16
constexpr long FO1_B  = 120295424;   // 32768 f
}

__device__ __forceinline__ unsigned short f2bf(float f) {
    union { float f; unsigned u; } v; v.f = f;
    unsigned r = v.u + 0x7FFFu + ((v.u >> 16) & 1u);
    return (unsigned short)(r >> 16);
}
__device__ __forceinline__ float bf2f(unsigned short s) {
    union { unsigned u; float f; } v; v.u = ((unsigned)s) << 16;
    return v.f;
}
__device__ __forceinline__ short8 cvt8(float4 a, float4 b) {
    float f[8] = {a.x, a.y, a.z, a.w, b.x, b.y, b.z, b.w};
    union { unsigned short s[8]; short8 v; } r;
#pragma unroll
    for (int i = 0; i < 8; ++i) r.s[i] = f2bf(f[i]);
    return r.v;
}
__device__ __forceinline__ uint2 pack4(float4 a) {
    union { unsigned short s[4]; uint2 u; } r;
    r.s[0] = f2bf(a.x); r.s[1] = f2bf(a.y); r.s[2] = f2bf(a.z); r.s[3] = f2bf(a.w);
    return r.u;
}

// ---------------- prep: zero stats + Lr + cheby bf16 repacks + conv2_w bf16 ----------------
__global__ void prep_kernel(const float* __restrict__ L0, const float* __restrict__ L1m,
                            const int* __restrict__ lmax0, const int* __restrict__ lmax1,
                            const float* __restrict__ cl1w, const float* __restrict__ cl2w,
                            const float* __restrict__ conv2w, float* __restrict__ ws)
{
    long idx = (long)blockIdx.x * 256 + threadIdx.x;
    float inv0 = 2.0f / (float)lmax0[0];
    float inv1 = 2.0f / (float)lmax1[0];
    char* wsb = (char*)ws;
    float* LR0p = (float*)(wsb + LR0_B);
    float* LR1p = (float*)(wsb + LR1_B);
    unsigned short* W1Rp = (unsigned short*)(wsb + W1RB_B);
    unsigned short* W2Rp = (unsigned short*)(wsb + W2RB_B);
    unsigned short* w2b  = (unsigned short*)(wsb + W2B_B);
    if (idx < 12288) {
        ws[idx] = 0.f;
    } else if (idx < 12288 + 4096) {
        long t = idx - 12288; int i = t / 64, j = t % 64;
        LR0p[t] = L0[t] * inv0 - (i == j ? 1.0f : 0.0f);
    } else if (idx < 12288 + 4096 + 1024) {
        long t = idx - 12288 - 4096; int i = t / 32, j = t % 32;
        LR1p[t] = L1m[t] * inv1 - (i == j ? 1.0f : 0.0f);
    } else if (idx < 12288 + 4096 + 1024 + 163840) {
        long t = idx - 12288 - 4096 - 1024;
        int k = t / 32768; int r = t % 32768; int o = r / 512, f = r % 512;
        W1Rp[t] = f2bf(cl1w[o * 2560 + f * 5 + k]);
    } else if (idx < 12288 + 4096 + 1024 + 163840 + 40960) {
        long t = idx - 12288 - 4096 - 1024 - 163840;
        int k = t / 8192; int r = t % 8192; int o = r / 64, f = r % 64;
        W2Rp[t] = f2bf(cl2w[o * 320 + f * 5 + k]);
    } else if (idx < 12288 + 4096 + 1024 + 163840 + 40960 + 2097152) {
        long t = idx - 12288 - 4096 - 1024 - 163840 - 40960;
        w2b[t] = f2bf(conv2w[t]);
    }
}

// ---------------- conv1 pass1: conv+relu+stats; block = (c, 8-batch group) ----------------
__global__ __launch_bounds__(256) void conv1_p1_kernel(const float* __restrict__ inp,
    const float* __restrict__ w1, const float* __restrict__ b1, float* __restrict__ ws)
{
    int c = blockIdx.x >> 3, bg = blockIdx.x & 7;
    __shared__ float xs[8][512];
    __shared__ float rs[8][32], rq[8][32];
    int tid = threadIdx.x;
#pragma unroll
    for (int it = 0; it < 4; ++it) {
        int f4 = it * 256 + tid;
        int bl = f4 >> 7, off = (f4 & 127) * 4;
        *(float4*)&xs[bl][off] = *(const float4*)&inp[((long)(bg * 8 + bl) * 64 + c) * 512 + off];
    }
    int o = tid & 31, bq = tid >> 5;
    int co = c * 32 + o;
    float w[16];
#pragma unroll
    for (int t = 0; t < 16; ++t) w[t] = w1[co * 16 + t];
    float bias = b1[co];
    __syncthreads();
    float s = 0.f, q = 0.f;
    for (int jg = 0; jg < 31; ++jg) {
        float x[32];
#pragma unroll
        for (int h = 0; h < 8; ++h) *(float4*)&x[h * 4] = *(const float4*)&xs[bq][jg * 16 + h * 4];
#pragma unroll
        for (int j = 0; j < 8; ++j) {
            float a = bias;
#pragma unroll
            for (int t = 0; t < 16; ++t) a = fmaf(x[2 * j + t], w[t], a);
            a = fmaxf(a, 0.f);
            s += a; q += a * a;
        }
    }
    {   // l = 248
        float x[16];
#pragma unroll
        for (int h = 0; h < 4; ++h) *(float4*)&x[h * 4] = *(const float4*)&xs[bq][496 + h * 4];
        float a = bias;
#pragma unroll
        for (int t = 0; t < 16; ++t) a = fmaf(x[t], w[t], a);
        a = fmaxf(a, 0.f);
        s += a; q += a * a;
    }
    rs[bq][o] = s; rq[bq][o] = q;
    __syncthreads();
    if (tid < 32) {
        float ss = 0.f, qq = 0.f;
#pragma unroll
        for (int i = 0; i < 8; ++i) { ss += rs[i][tid]; qq += rq[i][tid]; }
        atomicAdd(&ws[S1S + c * 32 + tid], ss);
        atomicAdd(&ws[S1Q + c * 32 + tid], qq);
    }
}

// ---------------- conv1 pass2: conv+bn+pool -> p1b bf16 [c][b][o][124] ----------------
__global__ __launch_bounds__(256) void conv1_p2_kernel(const float* __restrict__ inp,
    const float* __restrict__ w1, const float* __restrict__ b1,
    const float* __restrict__ g, const float* __restrict__ be,
    const float* __restrict__ ws, unsigned short* __restrict__ p1)
{
    int c = blockIdx.x >> 3, bg = blockIdx.x & 7;
    __shared__ float xs[8][512];
    int tid = threadIdx.x;
#pragma unroll
    for (int it = 0; it < 4; ++it) {
        int f4 = it * 256 + tid;
        int bl = f4 >> 7, off = (f4 & 127) * 4;
        *(float4*)&xs[bl][off] = *(const float4*)&inp[((long)(bg * 8 + bl) * 64 + c) * 512 + off];
    }
    int o = tid & 31, bq = tid >> 5;
    int co = c * 32 + o;
    float w[16];
#pragma unroll
    for (int t = 0; t < 16; ++t) w[t] = w1[co * 16 + t];
    float bias = b1[co];
    float N = (float)(Bn * L1O);
    float m = ws[S1S + co] / N;
    float inv = rsqrtf(ws[S1Q + co] / N - m * m + 1e-5f);
    float sc = inv * g[co], sh = be[co] - m * sc;
    __syncthreads();
    unsigned short* op = p1 + ((long)(c * 64 + bg * 8 + bq) * 32 + o) * 124;
    for (int jg = 0; jg < 31; ++jg) {
        float x[32];
#pragma unroll
        for (int h = 0; h < 8; ++h) *(float4*)&x[h * 4] = *(const float4*)&xs[bq][jg * 16 + h * 4];
        union { unsigned short r[4]; uint2 u; } pk;
#pragma unroll
        for (int p = 0; p < 4; ++p) {
            float a0 = bias, a1 = bias;
#pragma unroll
            for (int t = 0; t < 16; ++t) {
                a0 = fmaf(x[4 * p + t], w[t], a0);
                a1 = fmaf(x[4 * p + 2 + t], w[t], a1);
            }
            float v0 = fmaxf(a0, 0.f) * sc + sh;
            float v1 = fmaxf(a1, 0.f) * sc + sh;
            pk.r[p] = f2bf(fmaxf(v0, v1));
        }
        *(uint2*)&op[jg * 4] = pk.u;
    }
}

// ---------------- conv2 MFMA GEMM, M-tile 128 + relu + stats; y2 bf16 [c][b][l][o2] ----------------
__global__ __launch_bounds__(256) void conv2_mfma_kernel(const unsigned short* __restrict__ p1b,
    const unsigned short* __restrict__ w2b, const float* __restrict__ b2,
    unsigned short* __restrict__ y2b, float* __restrict__ s2s, float* __restrict__ s2q)
{
    int c = blockIdx.y;
    int m0 = blockIdx.x * 128;
    __shared__ unsigned short Bl[64 * 512];
    __shared__ float red[2][4][64];
    int tid = threadIdx.x;
    int w = tid >> 6, lane = tid & 63;
    int lx = lane & 15, g = lane >> 4;

    const unsigned short* wsrc = w2b + (long)c * 32768;
#pragma unroll
    for (int it = 0; it < 16; ++it) {
        int j = it * 256 + tid;
        int n = j >> 6, kb = j & 63;
        uint4 val = *(const uint4*)(wsrc + n * 512 + kb * 8);
        int dst = (n * 1024 + kb * 16) ^ ((n & 7) << 4);
        *(uint4*)((char*)Bl + dst) = val;
    }
    __syncthreads();

    const unsigned short* abase[2];
#pragma unroll
    for (int ma = 0; ma < 2; ++ma) {
        int m = m0 + w * 32 + ma * 16 + lx;
        m = min(m, 3519);
        int b = m / 55, lp = m % 55;
        abase[ma] = p1b + ((long)(c * 64 + b) * 32) * 124 + 2 * lp + (g & 1) * 8;
    }
    int cio = g >> 1;

    f32x4 acc[2][4] = {};
    for (int kstep = 0; kstep < 16; ++kstep) {
        short8 af[2];
#pragma unroll
        for (int ma = 0; ma < 2; ++ma) {
            const unsigned short* ap = abase[ma] + (kstep * 2 + cio) * 124;
            union { unsigned u[4]; short8 v; } t;
            t.u[0] = *(const unsigned*)(ap + 0);
            t.u[1] = *(const unsigned*)(ap + 2);
            t.u[2] = *(const unsigned*)(ap + 4);
            t.u[3] = *(const unsigned*)(ap + 6);
            af[ma] = t.v;
        }
#pragma unroll
        for (int fi = 0; fi < 4; ++fi) {
            int n = fi * 16 + lx;
            int off = (n * 1024 + kstep * 64 + g * 16) ^ ((n & 7) << 4);
            short8 bfrag = *(const short8*)((char*)Bl + off);
#pragma unroll
            for (int ma = 0; ma < 2; ++ma)
                acc[ma][fi] = __builtin_amdgcn_mfma_f32_16x16x32_bf16(af[ma], bfrag, acc[ma][fi], 0, 0, 0);
        }
    }

    float cs[4] = {}, cq[4] = {};
#pragma unroll
    for (int fi = 0; fi < 4; ++fi) {
        int o2 = fi * 16 + lx;
        float bia = b2[c * 64 + o2];
#pragma unroll
        for (int ma = 0; ma < 2; ++ma) {
#pragma unroll
            for (int r = 0; r < 4; ++r) {
                int mm = m0 + w * 32 + ma * 16 + g * 4 + r;
                if (mm < 3520) {
                    int bb = mm / 55, ll = mm % 55;
                    float y = fmaxf(acc[ma][fi][r] + bia, 0.f);
                    y2b[((long)(c * 64 + bb) * 55 + ll) * 64 + o2] = f2bf(y);
                    cs[fi] += y; cq[fi] += y * y;
                }
            }
        }
    }
#pragma unroll
    for (int fi = 0; fi < 4; ++fi) {
        cs[fi] += __shfl_xor(cs[fi], 16); cs[fi] += __shfl_xor(cs[fi], 32);
        cq[fi] += __shfl_xor(cq[fi], 16); cq[fi] += __shfl_xor(cq[fi], 32);
    }
    __syncthreads();
    if (g == 0) {
#pragma unroll
        for (int fi = 0; fi < 4; ++fi) { red[0][w][fi * 16 + lx] = cs[fi]; red[1][w][fi * 16 + lx] = cq[fi]; }
    }
    __syncthreads();
    if (tid < 64) {
        float ss = red[0][0][tid] + red[0][1][tid] + red[0][2][tid] + red[0][3][tid];
        float qq = red[1][0][tid] + red[1][1][tid] + red[1][2][tid] + red[1][3][tid];
        atomicAdd(&s2s[c * 64 + tid], ss);
        atomicAdd(&s2q[c * 64 + tid], qq);
    }
}

// ---------------- conv2 bn + pool via LDS transpose; block per (c,b) ----------------
// stage y2b tile [55][64] coalesced; write qb [o2*27+j] contiguous
__global__ __launch_bounds__(256) void bn2_pool_kernel(const unsigned short* __restrict__ y2b,
    const float* __restrict__ ws, const float* __restrict__ g, const float* __restrict__ be,
    unsigned short* __restrict__ q)
{
    int bid = blockIdx.x;              // c*64+b
    int c = bid >> 6;
    __shared__ unsigned short t2[55][66];
    const unsigned* src = (const unsigned*)(y2b + (long)bid * 3520);
    for (int i = threadIdx.x; i < 1760; i += 256) {
        int r = i >> 5, cu = i & 31;
        *(unsigned*)&t2[r][cu * 2] = src[i];
    }
    __syncthreads();
    float N = (float)(Bn * L2O);
    unsigned short* qp = q + (long)bid * 1728;
    for (int t = threadIdx.x; t < 1728; t += 256) {
        int o2 = t / 27, j = t - o2 * 27;
        int co = c * 64 + o2;
        float m = ws[S2S + co] / N;
        float inv = rsqrtf(ws[S2Q + co] / N - m * m + 1e-5f);
        float sc = inv * g[co], sh = be[co] - m * sc;
        float v = fmaxf(sc * bf2f(t2[2 * j][o2]) + sh, sc * bf2f(t2[2 * j + 1][o2]) + sh);
        qp[t] = f2bf(v);
    }
}

// ---------------- generic MFMA GEMM: C[64,Ntot] = relu(A_bf16[64,K] @ W_fp32[Ntot,K]^T + bias) ----------------
__global__ __launch_bounds__(256) void gemm_a16w32_kernel(const unsigned short* __restrict__ A,
    const float* __restrict__ W, const float* __restrict__ bias, float* __restrict__ C,
    int K, int Ntot, long sA, long sW, long sB, long sC)
{
    int c = blockIdx.y;
    A += (long)c * sA; W += (long)c * sW; bias += (long)c * sB; C += (long)c * sC;
    int n0 = blockIdx.x * 64;
    int tid = threadIdx.x, wv = tid >> 6, lane = tid & 63;
    int lx = lane & 15, g = lane >> 4;
    int wm = wv & 1, wn = wv >> 1;

    const unsigned short* a0 = A + (long)(wm * 32 + lx) * K + g * 8;
    const float* w0 = W + (long)(n0 + wn * 32 + lx) * K + g * 8;
    int ksteps = K >> 5;

    f32x4 acc[2][2] = {};
    for (int kstep = 0; kstep < ksteps; ++kstep) {
        short8 af[2];
        af[0] = *(const short8*)(a0 + kstep * 32);
        af[1] = *(const short8*)(a0 + (long)16 * K + kstep * 32);
        short8 bf[2];
#pragma unroll
        for (int nb = 0; nb < 2; ++nb) {
            const float* wp = w0 + (long)nb * 16 * K + kstep * 32;
            float4 x = *(const float4*)(wp);
            float4 y = *(const float4*)(wp + 4);
            bf[nb] = cvt8(x, y);
        }
#pragma unroll
        for (int ma = 0; ma < 2; ++ma)
#pragma unroll
            for (int nb = 0; nb < 2; ++nb)
                acc[ma][nb] = __builtin_amdgcn_mfma_f32_16x16x32_bf16(af[ma], bf[nb], acc[ma][nb], 0, 0, 0);
    }
#pragma unroll
    for (int ma = 0; ma < 2; ++ma)
#pragma unroll
        for (int nb = 0; nb < 2; ++nb) {
            int o = n0 + wn * 32 + nb * 16 + lx;
            float bia = bias[o];
#pragma unroll
            for (int r = 0; r < 4; ++r) {
                int b = wm * 32 + ma * 16 + g * 4 + r;
                C[(long)b * Ntot + o] = fmaxf(acc[ma][nb][r] + bia, 0.f);
            }
        }
}

// ---------------- fused chebyshev recursion V=64: x0..x4, bf16 stores ----------------
__global__ __launch_bounds__(256) void rec_fused_kernel(const float* __restrict__ Lr,
    const float* __restrict__ co, const int* __restrict__ perm, unsigned short* __restrict__ xkb)
{
    __shared__ float Lt[64 * 64];     // Lt[u][v] = Lr[v][u]
    __shared__ float xA[64][130];
    __shared__ float xB[64][130];
    int tid = threadIdx.x;
    for (int i = tid; i < 4096; i += 256) Lt[(i & 63) * 64 + (i >> 6)] = Lr[i];
    int cg = tid & 31, vg = tid >> 5;
    int col = blockIdx.x * 128 + cg * 4;
#pragma unroll
    for (int i = 0; i < 8; ++i) {
        int v = vg * 8 + i;
        float4 x = *(const float4*)&co[(long)perm[v] * 32768 + col];
        *(float4*)&xA[v][cg * 4] = x;
        *(uint2*)&xkb[(long)v * 32768 + col] = pack4(x);
    }
    __syncthreads();
#pragma unroll
    for (int k = 1; k <= 4; ++k) {
        float (*prev)[130] = (k & 1) ? xA : xB;
        float (*dst)[130]  = (k & 1) ? xB : xA;
        float acc[8][4] = {};
        for (int u = 0; u < 64; ++u) {
            float4 xv = *(const float4*)&prev[u][cg * 4];
            float4 l0 = *(const float4*)&Lt[u * 64 + vg * 8];
            float4 l1 = *(const float4*)&Lt[u * 64 + vg * 8 + 4];
            float lv[8] = {l0.x, l0.y, l0.z, l0.w, l1.x, l1.y, l1.z, l1.w};
#pragma unroll
            for (int i = 0; i < 8; ++i) {
                acc[i][0] = fmaf(lv[i], xv.x, acc[i][0]);
                acc[i][1] = fmaf(lv[i], xv.y, acc[i][1]);
                acc[i][2] = fmaf(lv[i], xv.z, acc[i][2]);
                acc[i][3] = fmaf(lv[i], xv.w, acc[i][3]);
            }
        }
#pragma unroll
        for (int i = 0; i < 8; ++i) {
            int v = vg * 8 + i;
            float4 r;
            if (k == 1) {
                r.x = acc[i][0]; r.y = acc[i][1]; r.z = acc[i][2]; r.w = acc[i][3];
            } else {
                float4 p = *(const float4*)&dst[v][cg * 4];   // holds x_{k-2}
                r.x = 2.f * acc[i][0] - p.x; r.y = 2.f * acc[i][1] - p.y;
                r.z = 2.f * acc[i][2] - p.z; r.w = 2.f * acc[i][3] - p.w;
            }
            *(float4*)&dst[v][cg * 4] = r;
            *(uint2*)&xkb[(long)k * 2097152 + (long)v * 32768 + col] = pack4(r);
        }
        __syncthreads();
    }
}

// ---------------- cheby layer-1 output GEMM, M-tile 16, bf16 A + bf16 weights ----------------
__global__ __launch_bounds__(256) void cheby1_mfma_kernel(const unsigned short* __restrict__ xkb,
    const unsigned short* __restrict__ w1rb, const float* __restrict__ bias, float* __restrict__ out)
{
    int m0 = blockIdx.x * 16;
    __shared__ unsigned short Bl[64 * 512];
    int tid = threadIdx.x, wv = tid >> 6, lane = tid & 63;
    int lx = lane & 15, g = lane >> 4;
    int m = m0 + lx;
    int v = m & 63, b = m >> 6;

    f32x4 acc = {};
    for (int kc = 0; kc < 5; ++kc) {
        __syncthreads();
#pragma unroll
        for (int it = 0; it < 16; ++it) {
            int j = it * 256 + tid;
            int n = j >> 6, kb = j & 63;
            uint4 val = *(const uint4*)(w1rb + (long)kc * 32768 + n * 512 + kb * 8);
            int dst = (n * 1024 + kb * 16) ^ ((n & 7) << 4);
            *(uint4*)((char*)Bl + dst) = val;
        }
        __syncthreads();
        const unsigned short* ab = xkb + (long)(kc * 64 + v) * 32768 + b * 512 + g * 8;
        for (int kl = 0; kl < 16; ++kl) {
            short8 af = *(const short8*)(ab + kl * 32);
            int n = wv * 16 + lx;
            int off = (n * 1024 + kl * 64 + g * 16) ^ ((n & 7) << 4);
            short8 bfrag = *(const short8*)((char*)Bl + off);
            acc = __builtin_amdgcn_mfma_f32_16x16x32_bf16(af, bfrag, acc, 0, 0, 0);
        }
    }
    int o = wv * 16 + lx;
    float bia = bias[o];
#pragma unroll
    for (int r = 0; r < 4; ++r) {
        int mm = m0 + g * 4 + r;
        int vv = mm & 63, bb = mm >> 6;
        out[((long)(bb * 64 + vv)) * 64 + o] = fmaxf(acc[r] + bia, 0.f);
    }
}

// ---------------- graph BN + graph max-pool (fp32 out, cheby layout) ----------------
template<int Fdim, int XOUT>
__global__ __launch_bounds__(256) void gbn_gpool_kernel(const float* __restrict__ y,
    const float* __restrict__ g, const float* __restrict__ be, float eps, int V, float* __restrict__ out)
{
    int j = blockIdx.x; int v0 = 2 * j;
    int tid = threadIdx.x;
    float s0 = 0.f, q0 = 0.f, s1 = 0.f, q1 = 0.f;
    int Ntot = Bn * Fdim;
    for (int idx = tid; idx < Ntot; idx += 256) {
        int b = idx / Fdim, f = idx % Fdim;
        float a = y[((long)b * V + v0) * Fdim + f];
        float c = y[((long)b * V + v0 + 1) * Fdim + f];
        s0 += a; q0 += a * a; s1 += c; q1 += c * c;
    }
    __shared__ float red[4][256];
    red[0][tid] = s0; red[1][tid] = q0; red[2][tid] = s1; red[3][tid] = q1;
    __syncthreads();
    for (int st = 128; st > 0; st >>= 1) {
        if (tid < st) {
#pragma unroll
            for (int r = 0; r < 4; ++r) red[r][tid] += red[r][tid + st];
        }
        __syncthreads();
    }
    float N = (float)Ntot;
    float m0 = red[0][0] / N, i0 = rsqrtf(red[1][0] / N - m0 * m0 + eps);
    float m1 = red[2][0] / N, i1 = rsqrtf(red[3][0] / N - m1 * m1 + eps);
    float sc0 = i0 * g[v0], sh0 = be[v0] - m0 * sc0;
    float sc1 = i1 * g[v0 + 1], sh1 = be[v0 + 1] - m1 * sc1;
    for (int idx = tid; idx < Ntot; idx += 256) {
        int b = idx / Fdim, f = idx % Fdim;
        float a = y[((long)b * V + v0) * Fdim + f];
        float c = y[((long)b * V + v0 + 1) * Fdim + f];
        float r = fmaxf(sc0 * a + sh0, sc1 * c + sh1);
        long oidx = XOUT ? ((long)j * Bn + b) * Fdim + f : ((long)b * (V / 2) + j) * Fdim + f;
        out[oidx] = r;
    }
}

// ---------------- gbn2 + gpool2, bf16 out [b][j*128+f] ----------------
__global__ __launch_bounds__(256) void gbn2_bf16_kernel(const float* __restrict__ y,
    const float* __restrict__ g, const float* __restrict__ be, unsigned short* __restrict__ out)
{
    constexpr int Fdim = 128; constexpr int V = 32;
    int j = blockIdx.x; int v0 = 2 * j;
    int tid = threadIdx.x;
    float s0 = 0.f, q0 = 0.f, s1 = 0.f, q1 = 0.f;
    int Ntot = Bn * Fdim;
    for (int idx = tid; idx < Ntot; idx += 256) {
        int b = idx / Fdim, f = idx % Fdim;
        float a = y[((long)b * V + v0) * Fdim + f];
        float c = y[((long)b * V + v0 + 1) * Fdim + f];
        s0 += a; q0 += a * a; s1 += c; q1 += c * c;
    }
    __shared__ float red[4][256];
    red[0][tid] = s0; red[1][tid] = q0; red[2][tid] = s1; red[3][tid] = q1;
    __syncthreads();
    for (int st = 128; st > 0; st >>= 1) {
        if (tid < st) {
#pragma unroll
            for (int r = 0; r < 4; ++r) red[r][tid] += red[r][tid + st];
        }
        __syncthreads();
    }
    float N = (float)Ntot;
    float m0 = red[0][0] / N, i0 = rsqrtf(red[1][0] / N - m0 * m0 + 128.0f);
    float m1 = red[2][0] / N, i1 = rsqrtf(red[3][0] / N - m1 * m1 + 128.0f);
    float sc0 = i0 * g[v0], sh0 = be[v0] - m0 * sc0;
    float sc1 = i1 * g[v0 + 1], sh1 = be[v0 + 1] - m1 * sc1;
    for (int idx = tid; idx < Ntot; idx += 256) {
        int b = idx / Fdim, f = idx % Fdim;
        float a = y[((long)b * V + v0) * Fdim + f];
        float c = y[((long)b * V + v0 + 1) * Fdim + f];
        float r = fmaxf(sc0 * a + sh0, sc1 * c + sh1);
        out[((long)b * 16 + j) * Fdim + f] = f2bf(r);
    }
}

// ---------------- fused layer 2: cheby recursion (LDS) + MFMA GEMM, one block per b ----------------
__global__ __launch_bounds__(256) void layer2_kernel(const float* __restrict__ x2k0,
    const float* __restrict__ Lr1, const unsigned short* __restrict__ w2rb,
    const float* __restrict__ bias, float* __restrict__ out)
{
    int b = blockIdx.x;
    __shared__ float xs[5][32][72];
    __shared__ unsigned short wsl[128 * 320];
    int tid = threadIdx.x;
#pragma unroll
    for (int it = 0; it < 20; ++it) {
        int j = it * 256 + tid;
        int o = j / 40, kb = j % 40;
        uint4 val = *(const uint4*)(w2rb + ((long)(kb >> 3) * 128 + o) * 64 + (kb & 7) * 8);
        int dst = (o * 640 + kb * 16) ^ ((o & 7) << 4);
        *(uint4*)((char*)wsl + dst) = val;
    }
    int v = tid & 31, fg = tid >> 5;
    float lrow[32];
#pragma unroll
    for (int u = 0; u < 32; ++u) lrow[u] = Lr1[v * 32 + u];
    {
        const float* sp = x2k0 + ((long)v * 64 + b) * 64 + fg * 8;
        float4 a = *(const float4*)sp;
        float4 c = *(const float4*)(sp + 4);
        *(float4*)&xs[0][v][fg * 8] = a;
        *(float4*)&xs[0][v][fg * 8 + 4] = c;
    }
    __syncthreads();
    for (int k = 1; k < 5; ++k) {
        float acc[8] = {};
#pragma unroll
        for (int u = 0; u < 32; ++u) {
            float4 xa = *(const float4*)&xs[k - 1][u][fg * 8];
            float4 xb = *(const float4*)&xs[k - 1][u][fg * 8 + 4];
            float l = lrow[u];
            acc[0] = fmaf(l, xa.x, acc[0]); acc[1] = fmaf(l, xa.y, acc[1]);
            acc[2] = fmaf(l, xa.z, acc[2]); acc[3] = fmaf(l, xa.w, acc[3]);
            acc[4] = fmaf(l, xb.x, acc[4]); acc[5] = fmaf(l, xb.y, acc[5]);
            acc[6] = fmaf(l, xb.z, acc[6]); acc[7] = fmaf(l, xb.w, acc[7]);
        }
        float4 ra, rb;
        if (k >= 2) {
            float4 pa = *(const float4*)&xs[k - 2][v][fg * 8];
            float4 pb = *(const float4*)&xs[k - 2][v][fg * 8 + 4];
            ra.x = 2.f * acc[0] - pa.x; ra.y = 2.f * acc[1] - pa.y;
            ra.z = 2.f * acc[2] - pa.z; ra.w = 2.f * acc[3] - pa.w;
            rb.x = 2.f * acc[4] - pb.x; rb.y = 2.f * acc[5] - pb.y;
            rb.z = 2.f * acc[6] - pb.z; rb.w = 2.f * acc[7] - pb.w;
        } else {
            ra.x = acc[0]; ra.y = acc[1]; ra.z = acc[2]; ra.w = acc[3];
            rb.x = acc[4]; rb.y = acc[5]; rb.z = acc[6]; rb.w = acc[7];
        }
        *(float4*)&xs[k][v][fg * 8] = ra;
        *(float4*)&xs[k][v][fg * 8 + 4] = rb;
        __syncthreads();
    }
    int wv = tid >> 6, lane = tid & 63;
    int lx = lane & 15, g = lane >> 4;
    f32x4 acc2[2][2] = {};
    for (int kstep = 0; kstep < 10; ++kstep) {
        int k = kstep * 32 + g * 8;
        int kc = k >> 6, f = k & 63;
        short8 af[2];
#pragma unroll
        for (int ma = 0; ma < 2; ++ma) {
            int vv = ma * 16 + lx;
            float4 xa = *(const float4*)&xs[kc][vv][f];
            float4 xb = *(const float4*)&xs[kc][vv][f + 4];
            af[ma] = cvt8(xa, xb);
        }
#pragma unroll
        for (int nb = 0; nb < 2; ++nb) {
            int o = wv * 32 + nb * 16 + lx;
            int kb = kstep * 4 + g;
            int off = (o * 640 + kb * 16) ^ ((o & 7) << 4);
            short8 bf = *(const short8*)((char*)wsl + off);
#pragma unroll
            for (int ma = 0; ma < 2; ++ma)
                acc2[ma][nb] = __builtin_amdgcn_mfma_f32_16x16x32_bf16(af[ma], bf, acc2[ma][nb], 0, 0, 0);
        }
    }
#pragma unroll
    for (int ma = 0; ma < 2; ++ma)
#pragma unroll
        for (int nb = 0; nb < 2; ++nb) {
            int o = wv * 32 + nb * 16 + lx;
            float bia = bias[o];
#pragma unroll
            for (int r = 0; r < 4; ++r) {
                int vv = ma * 16 + g * 4 + r;
                out[((long)b * 32 + vv) * 128 + o] = fmaxf(acc2[ma][nb][r] + bia, 0.f);
            }
        }
}

// ---------------- fc2 ----------------
__global__ void fc2_kernel(const float* __restrict__ x, const float* __restrict__ w,
                           const float* __restrict__ bv, float* __restrict__ out)
{
    int tid = threadIdx.x;   // 128 threads
    int b = tid >> 1, o = tid & 1;
    float acc = bv[o];
    for (int f = 0; f < 512; ++f) acc = fmaf(x[b * 512 + f], w[o * 512 + f], acc);
    out[tid] = acc;
}

// ---------------- launch ----------------
extern "C" void kernel_launch(void* const* d_in, const int* in_sizes, int n_in,
                              void* d_out, int out_size, void* d_ws, size_t ws_size,
                              hipStream_t stream)
{
    const float* inp    = (const float*)d_in[0];
    const float* L0     = (const float*)d_in[2];
    const float* L1m    = (const float*)d_in[3];
    const int*   lmax0  = (const int*)d_in[4];
    const int*   lmax1  = (const int*)d_in[5];
    const int*   perm   = (const int*)d_in[6];
    const float* conv1_w = (const float*)d_in[8];
    const float* conv1_b = (const float*)d_in[9];
    const float* bn1_g  = (const float*)d_in[10];
    const float* bn1_b  = (const float*)d_in[11];
    const float* conv2_w = (const float*)d_in[12];
    const float* conv2_b = (const float*)d_in[13];
    const float* bn2_g  = (const float*)d_in[14];
    const float* bn2_b  = (const float*)d_in[15];
    const float* lin1_w = (const float*)d_in[16];
    const float* lin1_b = (const float*)d_in[17];
    const float* cl1_w  = (const float*)d_in[18];
    const float* cl1_b  = (const float*)d_in[19];
    const float* gbn1_g = (const float*)d_in[20];
    const float* gbn1_b = (const float*)d_in[21];
    const float* cl2_w  = (const float*)d_in[22];
    const float* cl2_b  = (const float*)d_in[23];
    const float* gbn2_g = (const float*)d_in[24];
    const float* gbn2_b = (const float*)d_in[25];
    const float* fc1_w  = (const float*)d_in[26];
    const float* fc1_b  = (const float*)d_in[27];
    const float* fc2_w  = (const float*)d_in[28];
    const float* fc2_b  = (const float*)d_in[29];
    float* ws  = (float*)d_ws;
    char*  wsb = (char*)d_ws;
    float* out = (float*)d_out;

    unsigned short* w1rb = (unsigned short*)(wsb + W1RB_B);
    unsigned short* w2rb = (unsigned short*)(wsb + W2RB_B);
    unsigned short* w2b  = (unsigned short*)(wsb + W2B_B);
    unsigned short* p1b  = (unsigned short*)(wsb + P1B_B);
    unsigned short* y2b  = (unsigned short*)(wsb + Y2_B);
    unsigned short* qb   = (unsigned short*)(wsb + QB_B);
    float*          co   = (float*)(wsb + CO_B);
    unsigned short* xkb  = (unsigned short*)(wsb + XK_B);
    float*          ch1  = (float*)(wsb + CH1_B);
    float*          x2k0 = (float*)(wsb + X2K_B);
    float*          ch2  = (float*)(wsb + CH2_B);
    unsigned short* fci  = (unsigned short*)(wsb + FCI_B);
    float*          fo1  = (float*)(wsb + FO1_B);
    float*          lr0  = (float*)(wsb + LR0_B);
    float*          lr1  = (float*)(wsb + LR1_B);

    // 0. prep (zeros all stat accumulators + Lr + repacks)
    prep_kernel<<<9060, 256, 0, stream>>>(L0, L1m, lmax0, lmax1, cl1_w, cl2_w, conv2_w, ws);

    // 1. conv1: stats pass + bn/pool pass -> p1b bf16
    conv1_p1_kernel<<<512, 256, 0, stream>>>(inp, conv1_w, conv1_b, ws);
    conv1_p2_kernel<<<512, 256, 0, stream>>>(inp, conv1_w, conv1_b, bn1_g, bn1_b, ws, p1b);

    // 2. conv2 MFMA (M-tile 128) -> y2 bf16; bn+pool (LDS transpose) -> qb bf16
    conv2_mfma_kernel<<<dim3(28, 64), 256, 0, stream>>>(p1b, w2b, conv2_b, y2b, ws + S2S, ws + S2Q);
    bn2_pool_kernel<<<4096, 256, 0, stream>>>(y2b, ws, bn2_g, bn2_b, qb);

    // 3. lin1 MFMA -> co fp32
    gemm_a16w32_kernel<<<dim3(8, 64), 256, 0, stream>>>(qb, lin1_w, lin1_b, co,
        LIN1K, 512, (long)64 * LIN1K, (long)512 * LIN1K, 512, (long)64 * 512);

    // 4. cheby layer 1: fused recursion (bf16 xk stores) then MFMA output GEMM (bf16 A)
    rec_fused_kernel<<<256, 256, 0, stream>>>(lr0, co, perm, xkb);
    cheby1_mfma_kernel<<<256, 256, 0, stream>>>(xkb, w1rb, cl1_b, ch1);

    // 5. gbn1 + gpool1 -> x2k0 [v'][b][f]
    gbn_gpool_kernel<64, 1><<<32, 256, 0, stream>>>(ch1, gbn1_g, gbn1_b, 64.0f, 64, x2k0);

    // 6. fused layer 2 (recursion + cheby GEMM) -> ch2 [b][v][o]
    layer2_kernel<<<64, 256, 0, stream>>>(x2k0, lr1, w2rb, cl2_b, ch2);

    // 7. gbn2 + gpool2 -> fci bf16 [b][2048]
    gbn2_bf16_kernel<<<16, 256, 0, stream>>>(ch2, gbn2_g, gbn2_b, fci);

    // 8. fc1 MFMA + fc2
    gemm_a16w32_kernel<<<dim3(8, 1), 256, 0, stream>>>(fci, fc1_w, fc1_b, fo1,
        2048, 512, 0, 0, 0, 0);
    fc2_kernel<<<1, 128, 0, stream>>>(fo1, fc2_w, fc2_b, out);
}